// Round 8
// baseline (624.045 us; speedup 1.0000x reference)
//
#include <hip/hip_runtime.h>
#include <hip/hip_bf16.h>

// MoE: B=4,T=2048,D=768,E=8,F=3072,K=2.  N=8192 tokens, 16384 entries.
// Pipeline (7 launches):
//   prep      -> gates | pack W1 (256-row tiles) | pack W2 (256-row tiles)
//   scatter   -> buckets via wave-ballot aggregation
//   scan      -> tile table (expert, base) for <=72 entry-tiles of 256
//   pack_x    -> gathered x as swizzled [256][32]-chunk tiles (s1 B operand)
//   s1        -> 256(f)x256(entry) GEMM, wave tile 128x128, mfma 32x32x16,
//                BK=32, 3-buf counted-vmcnt, 1 barrier/step
//   s2        -> 256(d)x256(entry) GEMM, same schedule, 96 K-steps
//   combine   -> out = g0*b2[i0] + g1*b2[i1] + y[2t] + y[2t+1]

#define N_TOK 8192
#define D_DIM 768
#define E_EXP 8
#define F_DIM 3072
#define CAP   8192
#define NT2_MAX 72          // max 256-entry tiles: 16384/256 + 8 ceil slack

typedef __attribute__((ext_vector_type(8)))  short s8v;   // 8 x bf16
typedef __attribute__((ext_vector_type(16))) float f16v;  // 32x32 MFMA acc
typedef unsigned short u16;
typedef unsigned int   u32;
typedef unsigned long long u64;

static __device__ __forceinline__ u16 f2bf(float f) {
    u32 u = __float_as_uint(f);
    return (u16)((u + 0x7fffu + ((u >> 16) & 1u)) >> 16);   // RNE
}
static __device__ __forceinline__ float bf2f(u16 v) {
    return __uint_as_float((u32)v << 16);
}
// pack two f32 -> two bf16 (RNE) in one instruction
static __device__ __forceinline__ u32 cvt_pk_bf16(float lo, float hi) {
    u32 r;
    asm("v_cvt_pk_bf16_f32 %0, %1, %2" : "=v"(r) : "v"(lo), "v"(hi));
    return r;
}
// Branch-free erf-based GELU (A&S 7.1.26, |eps_erf| <= 1.5e-7).
static __device__ __forceinline__ float gelu_fast(float v) {
    const float av = fabsf(v);
    const float z  = av * 0.70710678118654752440f;
    const float t  = __builtin_amdgcn_rcpf(fmaf(0.3275911f, z, 1.0f));
    const float w  = __builtin_amdgcn_exp2f(-z * z * 1.4426950408889634f);
    float p = fmaf(1.061405429f, t, -1.453152027f);
    p = fmaf(p, t,  1.421413741f);
    p = fmaf(p, t, -0.284496736f);
    p = fmaf(p, t,  0.254829592f);
    p = p * t;
    const float E = 1.0f - p * w;       // erf(z), z >= 0
    return 0.5f * (v + av * E);
}
static __device__ __forceinline__ void gld_lds16(const u16* g, u16* l) {
    __builtin_amdgcn_global_load_lds(
        (const __attribute__((address_space(1))) void*)g,
        (__attribute__((address_space(3))) void*)l, 16, 0, 0);
}
template<int N> static __device__ __forceinline__ void wait_vmcnt() {
    asm volatile("s_waitcnt vmcnt(%0)" :: "n"(N) : "memory");
}
// asm barrier = HW barrier + compiler memory fence.
static __device__ __forceinline__ void bar_fenced() {
    asm volatile("s_barrier" ::: "memory");
}

// ---------------------------------------------------------------------------
// Fused prep (unchanged layout): gates | pack W1 | pack W2; block 0 zeros
// counts.  Packed chunk layout: [row][32 cols], col-group cg (4 x 8 bf16)
// stored at physical group (cg ^ ((row>>1)&3)).
// ---------------------------------------------------------------------------
__device__ __forceinline__ void pack_w_body(
    const float* __restrict__ src, u16* __restrict__ dst,
    int rt, int kc64, int e, int K1, int M2, int KC2, int TR, int ntm)
{
    __shared__ float ls[64][132];
    const float* se = src + (size_t)e * K1 * M2;
    const int tid = threadIdx.x;

    const int kr = tid >> 2, mq = tid & 3;
    const float* srow = se + (size_t)(kc64 * 64 + kr) * M2 + rt * 128 + mq * 32;
    #pragma unroll
    for (int it = 0; it < 8; ++it)
        *(float4*)&ls[kr][mq * 32 + it * 4] = *(const float4*)(srow + it * 4);
    __syncthreads();

    u16* dt_ = dst + ((size_t)(e * ntm + (rt * 128) / TR) * KC2 + kc64 * 2)
                     * ((size_t)TR * 32)
                   + (size_t)((rt * 128) % TR) * 32;
    const int rr = tid >> 1, hf = tid & 1;
    u16* dc = dt_ + (size_t)hf * TR * 32;
    const int row = ((rt * 128) % TR) + rr;
    #pragma unroll
    for (int j = 0; j < 4; ++j) {
        union { s8v v; u16 u[8]; } o;
        #pragma unroll
        for (int jj = 0; jj < 8; ++jj)
            o.u[jj] = f2bf(ls[hf * 32 + j * 8 + jj][rr]);
        *(s8v*)&dc[(size_t)rr * 32 + ((j ^ ((row >> 1) & 3)) * 8)] = o.v;
    }
}

__global__ __launch_bounds__(256) void prep_kernel(
    const float* __restrict__ x, const float* __restrict__ Wg,
    const float* __restrict__ bg, const float* __restrict__ W1,
    const float* __restrict__ W2, u32* __restrict__ rec_idx,
    float2* __restrict__ rec_g, u16* __restrict__ w1g,
    u16* __restrict__ w2g, int* __restrict__ counts)
{
    const int bid = blockIdx.x;
    if (bid == 0 && threadIdx.x < E_EXP) counts[threadIdx.x] = 0;

    if (bid < 2048) {
        // ------- gates -------
        const int wave = threadIdx.x >> 6;
        const int lane = threadIdx.x & 63;
        const int t = bid * 4 + wave;

        float acc[8];
        #pragma unroll
        for (int e = 0; e < 8; ++e) acc[e] = 0.f;

        const float* xrow = x + (size_t)t * D_DIM + lane * 12;
        #pragma unroll
        for (int i = 0; i < 3; ++i) {
            float4 xv = *(const float4*)(xrow + i * 4);
            float xs[4] = {xv.x, xv.y, xv.z, xv.w};
            #pragma unroll
            for (int j = 0; j < 4; ++j) {
                const int d = lane * 12 + i * 4 + j;
                const float4 w0 = *(const float4*)(Wg + (size_t)d * 8);
                const float4 w1 = *(const float4*)(Wg + (size_t)d * 8 + 4);
                acc[0] += xs[j] * w0.x;  acc[1] += xs[j] * w0.y;
                acc[2] += xs[j] * w0.z;  acc[3] += xs[j] * w0.w;
                acc[4] += xs[j] * w1.x;  acc[5] += xs[j] * w1.y;
                acc[6] += xs[j] * w1.z;  acc[7] += xs[j] * w1.w;
            }
        }
        #pragma unroll
        for (int e = 0; e < 8; ++e) {
            float v = acc[e];
            #pragma unroll
            for (int off = 32; off > 0; off >>= 1) v += __shfl_xor(v, off, 64);
            acc[e] = v + bg[e];
        }
        if (lane == 0) {
            float mx = acc[0];
            #pragma unroll
            for (int e = 1; e < 8; ++e) mx = fmaxf(mx, acc[e]);
            float p[8], s = 0.f;
            #pragma unroll
            for (int e = 0; e < 8; ++e) { p[e] = expf(acc[e] - mx); s += p[e]; }
            const float inv = 1.f / s;
            #pragma unroll
            for (int e = 0; e < 8; ++e) p[e] *= inv;

            int i0 = 0; float g0 = p[0];
            #pragma unroll
            for (int e = 1; e < 8; ++e) if (p[e] > g0) { g0 = p[e]; i0 = e; }
            int i1 = -1; float g1 = -1.f;
            #pragma unroll
            for (int e = 0; e < 8; ++e) if (e != i0 && p[e] > g1) { g1 = p[e]; i1 = e; }

            rec_idx[t] = (u32)i0 | ((u32)i1 << 4);
            rec_g[t] = make_float2(g0, g1);
        }
    } else if (bid < 4352) {
        // pack W1: [E][768][3072] -> 256-row tiles, KC2=24
        const int id = bid - 2048;               // e*288 + rt*12 + kc64
        const int e = id / 288, rem = id - e * 288;
        const int rt = rem / 12, kc = rem - rt * 12;
        pack_w_body(W1, w1g, rt, kc, e, D_DIM, F_DIM, 24, 256, 12);
    } else {
        // pack W2: [E][3072][768] -> 256-row tiles, KC2=96
        const int id = bid - 4352;               // e*288 + rt*48 + kc64
        const int e = id / 288, rem = id - e * 288;
        const int rt = rem / 48, kc = rem - rt * 48;
        pack_w_body(W2, w2g, rt, kc, e, F_DIM, D_DIM, 96, 256, 3);
    }
}

// ---------------------------------------------------------------------------
// Scatter: thread per token, wave-ballot aggregation -> <=8 atomics/wave.
// ---------------------------------------------------------------------------
__global__ __launch_bounds__(256) void moe_scatter(
    const u32* __restrict__ rec_idx, const float2* __restrict__ rec_g,
    int* __restrict__ counts, int* __restrict__ tokbuf,
    float* __restrict__ gatebuf)
{
    const int t = blockIdx.x * 256 + threadIdx.x;
    const int lane = threadIdx.x & 63;
    const u32 pk = rec_idx[t];
    const int i0 = pk & 15, i1 = (pk >> 4) & 15;
    const float2 g = rec_g[t];
    const u64 lmask = ((u64)1 << lane) - 1;

    #pragma unroll
    for (int e = 0; e < 8; ++e) {
        const u64 m0 = __ballot(i0 == e);
        const u64 m1 = __ballot(i1 == e);
        const int c0 = __popcll(m0);
        const int total = c0 + __popcll(m1);
        if (total > 0) {
            int base = 0;
            if (lane == 0) base = atomicAdd(&counts[e], total);
            base = __shfl(base, 0, 64);
            if (i0 == e) {
                const int p = base + __popcll(m0 & lmask);
                tokbuf[(size_t)e * CAP + p] = 2 * t;
                gatebuf[(size_t)e * CAP + p] = g.x;
            }
            if (i1 == e) {
                const int p = base + c0 + __popcll(m1 & lmask);
                tokbuf[(size_t)e * CAP + p] = 2 * t + 1;
                gatebuf[(size_t)e * CAP + p] = g.y;
            }
        }
    }
}

// tile table: for each expert, one tile per 256 entries
__global__ void scan_kernel(const int* __restrict__ counts,
                            int* __restrict__ te, int* __restrict__ tb,
                            int* __restrict__ ntile) {
    if (threadIdx.x == 0) {
        int nt = 0;
        for (int e = 0; e < E_EXP; ++e)
            for (int k = 0; k * 256 < counts[e]; ++k) {
                te[nt] = e; tb[nt] = k * 256; ++nt;
            }
        *ntile = nt;
    }
}

// ---------------------------------------------------------------------------
// pack_x: gather token rows -> swizzled bf16 [256][32]-chunk tiles.
// grid (NT2_MAX*2, 12): block = (tile, row-half) x 64 d-cols (2 chunks).
// ---------------------------------------------------------------------------
__global__ __launch_bounds__(256) void pack_x(
    const float* __restrict__ x, const int* __restrict__ counts,
    const int* __restrict__ te, const int* __restrict__ tb,
    const int* __restrict__ ntile, const int* __restrict__ tokbuf,
    u16* __restrict__ xg)
{
    const int bx2 = blockIdx.x, kc = blockIdx.y;
    const int bx = bx2 >> 1, rh = bx2 & 1;
    if (bx >= *ntile) return;
    const int e = te[bx], base = tb[bx], cnt = counts[e];
    const int tid = threadIdx.x;
    const int r = tid >> 1, hf = tid & 1;
    const int R = rh * 128 + r;
    int ent = base + R; if (ent >= cnt) ent = cnt - 1;
    const int tok = tokbuf[(size_t)e * CAP + ent] >> 1;
    const float* xr = x + (size_t)tok * D_DIM + kc * 64 + hf * 32;
    u16* xt = xg + ((size_t)bx * 24 + kc * 2 + hf) * 8192;
    #pragma unroll
    for (int j = 0; j < 4; ++j) {
        float4 a = *(const float4*)(xr + j * 8);
        float4 b = *(const float4*)(xr + j * 8 + 4);
        union { s8v v; u16 u[8]; } o;
        o.u[0] = f2bf(a.x); o.u[1] = f2bf(a.y); o.u[2] = f2bf(a.z); o.u[3] = f2bf(a.w);
        o.u[4] = f2bf(b.x); o.u[5] = f2bf(b.y); o.u[6] = f2bf(b.z); o.u[7] = f2bf(b.w);
        *(s8v*)&xt[(size_t)R * 32 + ((j ^ ((R >> 1) & 3)) * 8)] = o.v;
    }
}

// ---------------------------------------------------------------------------
// Shared GEMM step: 256(m)x256(n) block, 4 waves of 128x128, BK=32,
// mfma_f32_32x32x16_bf16 (acc 4x4 f32x16 tiles).
// Triple-buffered counted-vmcnt, one barrier/step:
//   vmcnt(8) [buf S done] -> barrier -> stage(S+2) -> 2x{8 ds_read, 16 MFMA}.
// Stage = 8 gld_lds/wave (4 A + 4 B, 16KB each panel).
// A/B fragment: lane l -> row/col = l&31, k-octet = l>>5 (k-permutation
// symmetric in A and B -> contraction correct regardless of HW octet order).
// LDS: 3 x (16KB A + 16KB B) = 96KB -> 1 block/CU.
// ---------------------------------------------------------------------------
#define G_STAGE(S, SBUF) do {                                                 \
    const int S__ = (S) < NS_ ? (S) : NS_ - 1;                                \
    const u16* An_ = Ab + (size_t)S__ * 8192 + w * 2048 + lane * 8;           \
    const u16* Bn_ = Bb + (size_t)S__ * 8192 + w * 2048 + lane * 8;           \
    u16* Ad_ = &Als[SBUF][w * 2048];                                          \
    u16* Bd_ = &Bls[SBUF][w * 2048];                                          \
    gld_lds16(An_,        Ad_);                                               \
    gld_lds16(An_ +  512, Ad_ +  512);                                        \
    gld_lds16(An_ + 1024, Ad_ + 1024);                                        \
    gld_lds16(An_ + 1536, Ad_ + 1536);                                        \
    gld_lds16(Bn_,        Bd_);                                               \
    gld_lds16(Bn_ +  512, Bd_ +  512);                                        \
    gld_lds16(Bn_ + 1024, Bd_ + 1024);                                        \
    gld_lds16(Bn_ + 1536, Bd_ + 1536);                                        \
} while (0)

#define G_STEP(S, BUF, B2) do {                                               \
    wait_vmcnt<8>();                                                          \
    bar_fenced();                                                             \
    G_STAGE((S) + 2, B2);                                                     \
    _Pragma("unroll")                                                         \
    for (int kk = 0; kk < 2; ++kk) {                                          \
        const int cswz = ((kk * 2 + hi) ^ ((r32 >> 1) & 3)) * 8;              \
        s8v af[4], bf[4];                                                     \
        _Pragma("unroll")                                                     \
        for (int mt = 0; mt < 4; ++mt)                                        \
            af[mt] = *(const s8v*)&Als[BUF][(wm*128 + mt*32 + r32)*32 + cswz];\
        _Pragma("unroll")                                                     \
        for (int nt = 0; nt < 4; ++nt)                                        \
            bf[nt] = *(const s8v*)&Bls[BUF][(wn*128 + nt*32 + r32)*32 + cswz];\
        __builtin_amdgcn_s_setprio(1);                                        \
        _Pragma("unroll")                                                     \
        for (int mt = 0; mt < 4; ++mt)                                        \
            _Pragma("unroll")                                                 \
            for (int nt = 0; nt < 4; ++nt)                                    \
                acc[mt][nt] = __builtin_amdgcn_mfma_f32_32x32x16_bf16(        \
                    af[mt], bf[nt], acc[mt][nt], 0, 0, 0);                    \
        __builtin_amdgcn_s_setprio(0);                                        \
    }                                                                         \
} while (0)

// ---------------------------------------------------------------------------
// Stage 1: per (entry-tile256, f-tile256): C[m=f 256][n=entry 256], K=768.
// 24 steps.  Epilogue: bias + GELU -> bf16 hg in s2-B 32-col layout.
// C layout (32x32): col = lane&31, row = (e&3) + 8*(e>>2) + 4*(lane>>5).
// ---------------------------------------------------------------------------
__global__ __launch_bounds__(256, 1) void s1_gemm(
    const u16* __restrict__ xg, const u16* __restrict__ w1g,
    const float* __restrict__ b1, const int* __restrict__ te,
    const int* __restrict__ ntile, u16* __restrict__ hg)
{
    __shared__ __align__(16) u16 Als[3][8192];   // 256 rows x 32 per buf
    __shared__ __align__(16) u16 Bls[3][8192];   // 256 rows x 32 per buf
    const int bx = blockIdx.x, by = blockIdx.y;   // by in [0,12): 256 f
    if (bx >= *ntile) return;
    const int e = te[bx];
    const int NS_ = 24;

    const int tid  = threadIdx.x;
    const int w    = tid >> 6;
    const int lane = tid & 63;
    const int wm   = w & 1, wn = w >> 1;          // wave grid 2(m) x 2(n)
    const int r32  = lane & 31, hi = lane >> 5;

    const u16* Ab = w1g + (size_t)(e * 12 + by) * 24 * 8192;
    const u16* Bb = xg  + (size_t)bx * 24 * 8192;

    f16v acc[4][4];
    #pragma unroll
    for (int mt = 0; mt < 4; ++mt)
        #pragma unroll
        for (int nt = 0; nt < 4; ++nt)
            #pragma unroll
            for (int ee = 0; ee < 16; ++ee) acc[mt][nt][ee] = 0.f;

    G_STAGE(0, 0);
    G_STAGE(1, 1);

    #pragma unroll 1
    for (int k = 0; k < 24; k += 3) {
        G_STEP(k,     0, 2);
        G_STEP(k + 1, 1, 0);
        G_STEP(k + 2, 2, 1);
    }
    wait_vmcnt<0>();

    // epilogue: f = by*256 + wm*128 + mt*32 + rq*8 + hi*4 + j (j=0..3)
    //           entry rr = wn*128 + nt*32 + r32
    const float* b1e = b1 + (size_t)e * F_DIM + by * 256;
    #pragma unroll
    for (int mt = 0; mt < 4; ++mt) {
        const int kc2 = by * 8 + wm * 4 + mt;      // 32-f chunk index
        u16* hc = hg + ((size_t)bx * 96 + kc2) * 8192;
        #pragma unroll
        for (int rq = 0; rq < 4; ++rq) {
            const int floc = wm * 128 + mt * 32 + rq * 8 + hi * 4;
            const float4 bv = *(const float4*)&b1e[floc];
            #pragma unroll
            for (int nt = 0; nt < 4; ++nt) {
                const int rr = wn * 128 + nt * 32 + r32;
                const int e0 = rq * 4;
                uint2 pk;
                pk.x = cvt_pk_bf16(gelu_fast(acc[mt][nt][e0]     + bv.x),
                                   gelu_fast(acc[mt][nt][e0 + 1] + bv.y));
                pk.y = cvt_pk_bf16(gelu_fast(acc[mt][nt][e0 + 2] + bv.z),
                                   gelu_fast(acc[mt][nt][e0 + 3] + bv.w));
                *(uint2*)&hc[(size_t)rr * 32 +
                             ((rq ^ ((rr >> 1) & 3)) * 8) + hi * 4] = pk;
            }
        }
    }
}

// ---------------------------------------------------------------------------
// Stage 2: per (entry-tile256, d-tile256): C[m=d 256][n=entry 256], K=3072.
// 96 steps.  Epilogue: y[tokslot][d] = gate * C (bf16 stores, no atomics).
// ---------------------------------------------------------------------------
__global__ __launch_bounds__(256, 1) void s2_gemm(
    const u16* __restrict__ hg, const u16* __restrict__ w2g,
    const int* __restrict__ counts, const int* __restrict__ te,
    const int* __restrict__ tb, const int* __restrict__ ntile,
    const int* __restrict__ tokbuf, const float* __restrict__ gatebuf,
    u16* __restrict__ y)
{
    __shared__ __align__(16) u16 Als[3][8192];
    __shared__ __align__(16) u16 Bls[3][8192];
    __shared__ int   sts[256];
    __shared__ float sg[256];
    const int bx = blockIdx.x, by = blockIdx.y;   // by in [0,3): 256 d
    if (bx >= *ntile) return;
    const int e = te[bx], base = tb[bx], cnt = counts[e];
    const int NS_ = 96;

    const int tid  = threadIdx.x;
    const int w    = tid >> 6;
    const int lane = tid & 63;
    const int wm   = w & 1, wn = w >> 1;
    const int r32  = lane & 31, hi = lane >> 5;

    {
        const int ent = base + tid;
        const bool v = ent < cnt;
        sts[tid] = v ? tokbuf[(size_t)e * CAP + ent] : -1;
        sg[tid]  = v ? gatebuf[(size_t)e * CAP + ent] : 0.f;
    }
    // drain prefetch loads so the vmcnt ledger below is exact
    asm volatile("s_waitcnt vmcnt(0) lgkmcnt(0)" ::: "memory");
    bar_fenced();

    const u16* Ab = w2g + (size_t)(e * 3 + by) * 96 * 8192;
    const u16* Bb = hg  + (size_t)bx * 96 * 8192;

    f16v acc[4][4];
    #pragma unroll
    for (int mt = 0; mt < 4; ++mt)
        #pragma unroll
        for (int nt = 0; nt < 4; ++nt)
            #pragma unroll
            for (int ee = 0; ee < 16; ++ee) acc[mt][nt][ee] = 0.f;

    G_STAGE(0, 0);
    G_STAGE(1, 1);

    #pragma unroll 1
    for (int k = 0; k < 96; k += 3) {
        G_STEP(k,     0, 2);
        G_STEP(k + 1, 1, 0);
        G_STEP(k + 2, 2, 1);
    }
    wait_vmcnt<0>();

    // epilogue: d = by*256 + wm*128 + mt*32 + rq*8 + hi*4 + j
    //           entry rr = wn*128 + nt*32 + r32
    #pragma unroll
    for (int nt = 0; nt < 4; ++nt) {
        const int rr = wn * 128 + nt * 32 + r32;
        const int ts = sts[rr];
        if (ts >= 0) {
            const float g = sg[rr];
            u16* yr = y + (size_t)ts * D_DIM + by * 256 + wm * 128 + hi * 4;
            #pragma unroll
            for (int mt = 0; mt < 4; ++mt)
                #pragma unroll
                for (int rq = 0; rq < 4; ++rq) {
                    const int e0 = rq * 4;
                    uint2 pk;
                    pk.x = cvt_pk_bf16(g * acc[mt][nt][e0],
                                       g * acc[mt][nt][e0 + 1]);
                    pk.y = cvt_pk_bf16(g * acc[mt][nt][e0 + 2],
                                       g * acc[mt][nt][e0 + 3]);
                    *(uint2*)&yr[mt * 32 + rq * 8] = pk;
                }
        }
    }
}

// out = g0*b2[i0] + g1*b2[i1] + y[2t] + y[2t+1]
__global__ __launch_bounds__(256) void combine_kernel(
    const u16* __restrict__ y, const u32* __restrict__ rec_idx,
    const float2* __restrict__ rec_g, const float* __restrict__ b2,
    float* __restrict__ out)
{
    const int gid = blockIdx.x * 256 + threadIdx.x;
    const int t = gid / 192;
    const int c = (gid - t * 192) * 4;
    const u32 pk = rec_idx[t];
    const int i0 = pk & 15, i1 = (pk >> 4) & 15;
    const float2 g = rec_g[t];
    union { uint2 p; u16 u[4]; } a, b;
    a.p = *(const uint2*)&y[(size_t)(2 * t) * D_DIM + c];
    b.p = *(const uint2*)&y[(size_t)(2 * t + 1) * D_DIM + c];
    const float4 ba = *(const float4*)&b2[(size_t)i0 * D_DIM + c];
    const float4 bb = *(const float4*)&b2[(size_t)i1 * D_DIM + c];
    float4 o;
    o.x = g.x * ba.x + g.y * bb.x + bf2f(a.u[0]) + bf2f(b.u[0]);
    o.y = g.x * ba.y + g.y * bb.y + bf2f(a.u[1]) + bf2f(b.u[1]);
    o.z = g.x * ba.z + g.y * bb.z + bf2f(a.u[2]) + bf2f(b.u[2]);
    o.w = g.x * ba.w + g.y * bb.w + bf2f(a.u[3]) + bf2f(b.u[3]);
    *(float4*)&out[(size_t)t * D_DIM + c] = o;
}

// ---------------------------------------------------------------------------
extern "C" void kernel_launch(void* const* d_in, const int* in_sizes, int n_in,
                              void* d_out, int out_size, void* d_ws, size_t ws_size,
                              hipStream_t stream) {
    const float* x  = (const float*)d_in[0];
    const float* Wg = (const float*)d_in[1];
    const float* bg = (const float*)d_in[2];
    const float* W1 = (const float*)d_in[3];
    const float* b1 = (const float*)d_in[4];
    const float* W2 = (const float*)d_in[5];
    const float* b2 = (const float*)d_in[6];
    float* out = (float*)d_out;

    // ws layout (~243 MB)
    char* ws = (char*)d_ws;
    size_t off = 0;
    u16* xg  = (u16*)(ws + off); off += (size_t)NT2_MAX * 24 * 8192 * sizeof(u16);
    u16* w1g = (u16*)(ws + off); off += (size_t)E_EXP * F_DIM * D_DIM * sizeof(u16);
    u16* w2g = (u16*)(ws + off); off += (size_t)E_EXP * D_DIM * F_DIM * sizeof(u16);
    u16* hg  = (u16*)(ws + off); off += (size_t)NT2_MAX * 96 * 8192 * sizeof(u16);
    u16* y   = (u16*)(ws + off); off += (size_t)2 * N_TOK * D_DIM * sizeof(u16);
    int* tokbuf = (int*)(ws + off);      off += (size_t)E_EXP * CAP * sizeof(int);
    float* gatebuf = (float*)(ws + off); off += (size_t)E_EXP * CAP * sizeof(float);
    u32* rec_idx = (u32*)(ws + off);     off += (size_t)N_TOK * sizeof(u32);
    float2* rec_g = (float2*)(ws + off); off += (size_t)N_TOK * sizeof(float2);
    int* counts = (int*)(ws + off);      off += 64;
    int* te     = (int*)(ws + off);      off += NT2_MAX * sizeof(int);
    int* tb     = (int*)(ws + off);      off += NT2_MAX * sizeof(int);
    int* ntile  = (int*)(ws + off);      off += 64;

    prep_kernel<<<6656, 256, 0, stream>>>(x, Wg, bg, W1, W2, rec_idx, rec_g,
                                          w1g, w2g, counts);
    moe_scatter<<<N_TOK / 256, 256, 0, stream>>>(rec_idx, rec_g, counts, tokbuf, gatebuf);
    scan_kernel<<<1, 64, 0, stream>>>(counts, te, tb, ntile);
    pack_x<<<dim3(NT2_MAX * 2, 12), 256, 0, stream>>>(x, counts, te, tb, ntile,
                                                      tokbuf, xg);

    s1_gemm<<<dim3(NT2_MAX, 12), 256, 0, stream>>>(xg, w1g, b1, te, ntile, hg);
    s2_gemm<<<dim3(NT2_MAX, 3), 256, 0, stream>>>(hg, w2g, counts, te, tb, ntile,
                                                  tokbuf, gatebuf, y);
    combine_kernel<<<(N_TOK * 192) / 256, 256, 0, stream>>>(y, rec_idx, rec_g, b2, out);
}

// Round 9
// 618.081 us; speedup vs baseline: 1.0096x; 1.0096x over previous
//
#include <hip/hip_runtime.h>
#include <hip/hip_bf16.h>

// MoE: B=4,T=2048,D=768,E=8,F=3072,K=2.  N=8192 tokens, 16384 entries.
// Pipeline (7 launches):
//   prep      -> gates | pack W1 (256-row tiles) | pack W2 (256-row tiles)
//   scatter   -> buckets via wave-ballot aggregation
//   scan      -> tile table (expert, base) for <=72 entry-tiles of 256
//   pack_x    -> gathered x as k-octet-major [4][256][16B] chunk tiles
//   s1        -> 256(f)x256(entry) GEMM, wave tile 128x128, mfma 32x32x16,
//                BK=32, 3-buf counted-vmcnt, 1 barrier/step
//   s2        -> 256(d)x256(entry) GEMM, same schedule, 96 K-steps
//   combine   -> out = g0*b2[i0] + g1*b2[i1] + y[2t] + y[2t+1]
//
// Chunk layout (16KB = 32 k x 256 rows bf16): OCTET-MAJOR
//   u16 offset = oct*2048 + row*8,  oct = k_local>>3 (0..3), 16B per (oct,row).
//   Fragment ds_read_b128: half-wave reads 32 consecutive rows of one octet
//   plane -> contiguous 512B -> conflict-free (hi halves alias banks 2-way,
//   free per m136).  No XOR swizzle anywhere.

#define N_TOK 8192
#define D_DIM 768
#define E_EXP 8
#define F_DIM 3072
#define CAP   8192
#define NT2_MAX 72          // max 256-entry tiles: 16384/256 + 8 ceil slack

typedef __attribute__((ext_vector_type(8)))  short s8v;   // 8 x bf16
typedef __attribute__((ext_vector_type(16))) float f16v;  // 32x32 MFMA acc
typedef unsigned short u16;
typedef unsigned int   u32;
typedef unsigned long long u64;

static __device__ __forceinline__ u16 f2bf(float f) {
    u32 u = __float_as_uint(f);
    return (u16)((u + 0x7fffu + ((u >> 16) & 1u)) >> 16);   // RNE
}
static __device__ __forceinline__ float bf2f(u16 v) {
    return __uint_as_float((u32)v << 16);
}
// pack two f32 -> two bf16 (RNE) in one instruction
static __device__ __forceinline__ u32 cvt_pk_bf16(float lo, float hi) {
    u32 r;
    asm("v_cvt_pk_bf16_f32 %0, %1, %2" : "=v"(r) : "v"(lo), "v"(hi));
    return r;
}
// Branch-free erf-based GELU (A&S 7.1.26, |eps_erf| <= 1.5e-7).
static __device__ __forceinline__ float gelu_fast(float v) {
    const float av = fabsf(v);
    const float z  = av * 0.70710678118654752440f;
    const float t  = __builtin_amdgcn_rcpf(fmaf(0.3275911f, z, 1.0f));
    const float w  = __builtin_amdgcn_exp2f(-z * z * 1.4426950408889634f);
    float p = fmaf(1.061405429f, t, -1.453152027f);
    p = fmaf(p, t,  1.421413741f);
    p = fmaf(p, t, -0.284496736f);
    p = fmaf(p, t,  0.254829592f);
    p = p * t;
    const float E = 1.0f - p * w;       // erf(z), z >= 0
    return 0.5f * (v + av * E);
}
static __device__ __forceinline__ void gld_lds16(const u16* g, u16* l) {
    __builtin_amdgcn_global_load_lds(
        (const __attribute__((address_space(1))) void*)g,
        (__attribute__((address_space(3))) void*)l, 16, 0, 0);
}
template<int N> static __device__ __forceinline__ void wait_vmcnt() {
    asm volatile("s_waitcnt vmcnt(%0)" :: "n"(N) : "memory");
}
// asm barrier = HW barrier + compiler memory fence.
static __device__ __forceinline__ void bar_fenced() {
    asm volatile("s_barrier" ::: "memory");
}

// ---------------------------------------------------------------------------
// Fused prep: gates | pack W1 | pack W2; block 0 zeros counts.
// Pack body writes octet-major chunks (see header comment).
// ---------------------------------------------------------------------------
__device__ __forceinline__ void pack_w_body(
    const float* __restrict__ src, u16* __restrict__ dst,
    int rt, int kc64, int e, int K1, int M2, int KC2, int TR, int ntm)
{
    __shared__ float ls[64][132];
    const float* se = src + (size_t)e * K1 * M2;
    const int tid = threadIdx.x;

    const int kr = tid >> 2, mq = tid & 3;
    const float* srow = se + (size_t)(kc64 * 64 + kr) * M2 + rt * 128 + mq * 32;
    #pragma unroll
    for (int it = 0; it < 8; ++it)
        *(float4*)&ls[kr][mq * 32 + it * 4] = *(const float4*)(srow + it * 4);
    __syncthreads();

    const int rr = tid >> 1, hf = tid & 1;
    // chunk = kc64*2 + hf; octet-major within chunk
    u16* dc = dst + ((size_t)(e * ntm + (rt * 128) / TR) * KC2 + kc64 * 2 + hf)
                     * ((size_t)TR * 32);
    const int row = ((rt * 128) % TR) + rr;
    #pragma unroll
    for (int j = 0; j < 4; ++j) {        // j = k-octet within chunk
        union { s8v v; u16 u[8]; } o;
        #pragma unroll
        for (int jj = 0; jj < 8; ++jj)
            o.u[jj] = f2bf(ls[hf * 32 + j * 8 + jj][rr]);
        *(s8v*)&dc[(size_t)j * (TR * 8) + (size_t)row * 8] = o.v;
    }
}

__global__ __launch_bounds__(256) void prep_kernel(
    const float* __restrict__ x, const float* __restrict__ Wg,
    const float* __restrict__ bg, const float* __restrict__ W1,
    const float* __restrict__ W2, u32* __restrict__ rec_idx,
    float2* __restrict__ rec_g, u16* __restrict__ w1g,
    u16* __restrict__ w2g, int* __restrict__ counts)
{
    const int bid = blockIdx.x;
    if (bid == 0 && threadIdx.x < E_EXP) counts[threadIdx.x] = 0;

    if (bid < 2048) {
        // ------- gates -------
        const int wave = threadIdx.x >> 6;
        const int lane = threadIdx.x & 63;
        const int t = bid * 4 + wave;

        float acc[8];
        #pragma unroll
        for (int e = 0; e < 8; ++e) acc[e] = 0.f;

        const float* xrow = x + (size_t)t * D_DIM + lane * 12;
        #pragma unroll
        for (int i = 0; i < 3; ++i) {
            float4 xv = *(const float4*)(xrow + i * 4);
            float xs[4] = {xv.x, xv.y, xv.z, xv.w};
            #pragma unroll
            for (int j = 0; j < 4; ++j) {
                const int d = lane * 12 + i * 4 + j;
                const float4 w0 = *(const float4*)(Wg + (size_t)d * 8);
                const float4 w1 = *(const float4*)(Wg + (size_t)d * 8 + 4);
                acc[0] += xs[j] * w0.x;  acc[1] += xs[j] * w0.y;
                acc[2] += xs[j] * w0.z;  acc[3] += xs[j] * w0.w;
                acc[4] += xs[j] * w1.x;  acc[5] += xs[j] * w1.y;
                acc[6] += xs[j] * w1.z;  acc[7] += xs[j] * w1.w;
            }
        }
        #pragma unroll
        for (int e = 0; e < 8; ++e) {
            float v = acc[e];
            #pragma unroll
            for (int off = 32; off > 0; off >>= 1) v += __shfl_xor(v, off, 64);
            acc[e] = v + bg[e];
        }
        if (lane == 0) {
            float mx = acc[0];
            #pragma unroll
            for (int e = 1; e < 8; ++e) mx = fmaxf(mx, acc[e]);
            float p[8], s = 0.f;
            #pragma unroll
            for (int e = 0; e < 8; ++e) { p[e] = expf(acc[e] - mx); s += p[e]; }
            const float inv = 1.f / s;
            #pragma unroll
            for (int e = 0; e < 8; ++e) p[e] *= inv;

            int i0 = 0; float g0 = p[0];
            #pragma unroll
            for (int e = 1; e < 8; ++e) if (p[e] > g0) { g0 = p[e]; i0 = e; }
            int i1 = -1; float g1 = -1.f;
            #pragma unroll
            for (int e = 0; e < 8; ++e) if (e != i0 && p[e] > g1) { g1 = p[e]; i1 = e; }

            rec_idx[t] = (u32)i0 | ((u32)i1 << 4);
            rec_g[t] = make_float2(g0, g1);
        }
    } else if (bid < 4352) {
        // pack W1: [E][768][3072] -> 256-row tiles, KC2=24
        const int id = bid - 2048;               // e*288 + rt*12 + kc64
        const int e = id / 288, rem = id - e * 288;
        const int rt = rem / 12, kc = rem - rt * 12;
        pack_w_body(W1, w1g, rt, kc, e, D_DIM, F_DIM, 24, 256, 12);
    } else {
        // pack W2: [E][3072][768] -> 256-row tiles, KC2=96
        const int id = bid - 4352;               // e*288 + rt*48 + kc64
        const int e = id / 288, rem = id - e * 288;
        const int rt = rem / 48, kc = rem - rt * 48;
        pack_w_body(W2, w2g, rt, kc, e, F_DIM, D_DIM, 96, 256, 3);
    }
}

// ---------------------------------------------------------------------------
// Scatter: thread per token, wave-ballot aggregation -> <=8 atomics/wave.
// ---------------------------------------------------------------------------
__global__ __launch_bounds__(256) void moe_scatter(
    const u32* __restrict__ rec_idx, const float2* __restrict__ rec_g,
    int* __restrict__ counts, int* __restrict__ tokbuf,
    float* __restrict__ gatebuf)
{
    const int t = blockIdx.x * 256 + threadIdx.x;
    const int lane = threadIdx.x & 63;
    const u32 pk = rec_idx[t];
    const int i0 = pk & 15, i1 = (pk >> 4) & 15;
    const float2 g = rec_g[t];
    const u64 lmask = ((u64)1 << lane) - 1;

    #pragma unroll
    for (int e = 0; e < 8; ++e) {
        const u64 m0 = __ballot(i0 == e);
        const u64 m1 = __ballot(i1 == e);
        const int c0 = __popcll(m0);
        const int total = c0 + __popcll(m1);
        if (total > 0) {
            int base = 0;
            if (lane == 0) base = atomicAdd(&counts[e], total);
            base = __shfl(base, 0, 64);
            if (i0 == e) {
                const int p = base + __popcll(m0 & lmask);
                tokbuf[(size_t)e * CAP + p] = 2 * t;
                gatebuf[(size_t)e * CAP + p] = g.x;
            }
            if (i1 == e) {
                const int p = base + c0 + __popcll(m1 & lmask);
                tokbuf[(size_t)e * CAP + p] = 2 * t + 1;
                gatebuf[(size_t)e * CAP + p] = g.y;
            }
        }
    }
}

// tile table: for each expert, one tile per 256 entries
__global__ void scan_kernel(const int* __restrict__ counts,
                            int* __restrict__ te, int* __restrict__ tb,
                            int* __restrict__ ntile) {
    if (threadIdx.x == 0) {
        int nt = 0;
        for (int e = 0; e < E_EXP; ++e)
            for (int k = 0; k * 256 < counts[e]; ++k) {
                te[nt] = e; tb[nt] = k * 256; ++nt;
            }
        *ntile = nt;
    }
}

// ---------------------------------------------------------------------------
// pack_x: gather token rows -> octet-major bf16 [4][256][16B] chunk tiles.
// grid (NT2_MAX*2, 12): block = (tile, row-half) x 64 d-cols (2 chunks).
// ---------------------------------------------------------------------------
__global__ __launch_bounds__(256) void pack_x(
    const float* __restrict__ x, const int* __restrict__ counts,
    const int* __restrict__ te, const int* __restrict__ tb,
    const int* __restrict__ ntile, const int* __restrict__ tokbuf,
    u16* __restrict__ xg)
{
    const int bx2 = blockIdx.x, kc = blockIdx.y;
    const int bx = bx2 >> 1, rh = bx2 & 1;
    if (bx >= *ntile) return;
    const int e = te[bx], base = tb[bx], cnt = counts[e];
    const int tid = threadIdx.x;
    const int r = tid >> 1, hf = tid & 1;
    const int R = rh * 128 + r;
    int ent = base + R; if (ent >= cnt) ent = cnt - 1;
    const int tok = tokbuf[(size_t)e * CAP + ent] >> 1;
    const float* xr = x + (size_t)tok * D_DIM + kc * 64 + hf * 32;
    u16* xt = xg + ((size_t)bx * 24 + kc * 2 + hf) * 8192;
    #pragma unroll
    for (int j = 0; j < 4; ++j) {        // j = k-octet
        float4 a = *(const float4*)(xr + j * 8);
        float4 b = *(const float4*)(xr + j * 8 + 4);
        union { s8v v; u16 u[8]; } o;
        o.u[0] = f2bf(a.x); o.u[1] = f2bf(a.y); o.u[2] = f2bf(a.z); o.u[3] = f2bf(a.w);
        o.u[4] = f2bf(b.x); o.u[5] = f2bf(b.y); o.u[6] = f2bf(b.z); o.u[7] = f2bf(b.w);
        *(s8v*)&xt[(size_t)j * 2048 + (size_t)R * 8] = o.v;
    }
}

// ---------------------------------------------------------------------------
// Shared GEMM step: 256(m)x256(n) block, 4 waves of 128x128, BK=32,
// mfma_f32_32x32x16_bf16 (acc 4x4 f32x16 tiles).
// Triple-buffered counted-vmcnt, one barrier/step:
//   vmcnt(8) [buf S done] -> barrier -> stage(S+2) -> 2x{8 ds_read, 16 MFMA}.
// Fragment read: lane (r32,hi), octet kk*2+hi -> contiguous 512B/half-wave.
// LDS: 3 x (16KB A + 16KB B) = 96KB -> 1 block/CU.
// ---------------------------------------------------------------------------
#define G_STAGE(S, SBUF) do {                                                 \
    const int S__ = (S) < NS_ ? (S) : NS_ - 1;                                \
    const u16* An_ = Ab + (size_t)S__ * 8192 + w * 2048 + lane * 8;           \
    const u16* Bn_ = Bb + (size_t)S__ * 8192 + w * 2048 + lane * 8;           \
    u16* Ad_ = &Als[SBUF][w * 2048];                                          \
    u16* Bd_ = &Bls[SBUF][w * 2048];                                          \
    gld_lds16(An_,        Ad_);                                               \
    gld_lds16(An_ +  512, Ad_ +  512);                                        \
    gld_lds16(An_ + 1024, Ad_ + 1024);                                        \
    gld_lds16(An_ + 1536, Ad_ + 1536);                                        \
    gld_lds16(Bn_,        Bd_);                                               \
    gld_lds16(Bn_ +  512, Bd_ +  512);                                        \
    gld_lds16(Bn_ + 1024, Bd_ + 1024);                                        \
    gld_lds16(Bn_ + 1536, Bd_ + 1536);                                        \
} while (0)

#define G_STEP(S, BUF, B2) do {                                               \
    wait_vmcnt<8>();                                                          \
    bar_fenced();                                                             \
    G_STAGE((S) + 2, B2);                                                     \
    _Pragma("unroll")                                                         \
    for (int kk = 0; kk < 2; ++kk) {                                          \
        const int kof = kk * 4096 + hi * 2048;    /* octet plane (u16) */     \
        s8v af[4], bf[4];                                                     \
        _Pragma("unroll")                                                     \
        for (int mt = 0; mt < 4; ++mt)                                        \
            af[mt] = *(const s8v*)&Als[BUF][kof + (wm*128 + mt*32 + r32)*8];  \
        _Pragma("unroll")                                                     \
        for (int nt = 0; nt < 4; ++nt)                                        \
            bf[nt] = *(const s8v*)&Bls[BUF][kof + (wn*128 + nt*32 + r32)*8];  \
        __builtin_amdgcn_s_setprio(1);                                        \
        _Pragma("unroll")                                                     \
        for (int mt = 0; mt < 4; ++mt)                                        \
            _Pragma("unroll")                                                 \
            for (int nt = 0; nt < 4; ++nt)                                    \
                acc[mt][nt] = __builtin_amdgcn_mfma_f32_32x32x16_bf16(        \
                    af[mt], bf[nt], acc[mt][nt], 0, 0, 0);                    \
        __builtin_amdgcn_s_setprio(0);                                        \
    }                                                                         \
} while (0)

// ---------------------------------------------------------------------------
// Stage 1: per (entry-tile256, f-tile256): C[m=f 256][n=entry 256], K=768.
// 24 steps.  Epilogue: bias + GELU -> bf16 hg in s2-B octet-major layout.
// C layout (32x32): col = lane&31, row = (reg&3) + 8*(reg>>2) + 4*(lane>>5).
// ---------------------------------------------------------------------------
__global__ __launch_bounds__(256, 1) void s1_gemm(
    const u16* __restrict__ xg, const u16* __restrict__ w1g,
    const float* __restrict__ b1, const int* __restrict__ te,
    const int* __restrict__ ntile, u16* __restrict__ hg)
{
    __shared__ __align__(16) u16 Als[3][8192];   // 16KB chunk per buf
    __shared__ __align__(16) u16 Bls[3][8192];
    const int bx = blockIdx.x, by = blockIdx.y;   // by in [0,12): 256 f
    if (bx >= *ntile) return;
    const int e = te[bx];
    const int NS_ = 24;

    const int tid  = threadIdx.x;
    const int w    = tid >> 6;
    const int lane = tid & 63;
    const int wm   = w & 1, wn = w >> 1;          // wave grid 2(m) x 2(n)
    const int r32  = lane & 31, hi = lane >> 5;

    const u16* Ab = w1g + (size_t)(e * 12 + by) * 24 * 8192;
    const u16* Bb = xg  + (size_t)bx * 24 * 8192;

    f16v acc[4][4];
    #pragma unroll
    for (int mt = 0; mt < 4; ++mt)
        #pragma unroll
        for (int nt = 0; nt < 4; ++nt)
            #pragma unroll
            for (int ee = 0; ee < 16; ++ee) acc[mt][nt][ee] = 0.f;

    G_STAGE(0, 0);
    G_STAGE(1, 1);

    #pragma unroll 1
    for (int k = 0; k < 24; k += 3) {
        G_STEP(k,     0, 2);
        G_STEP(k + 1, 1, 0);
        G_STEP(k + 2, 2, 1);
    }
    wait_vmcnt<0>();

    // epilogue: f = by*256 + wm*128 + mt*32 + rq*8 + hi*4 + j (j=0..3)
    //           entry rr = wn*128 + nt*32 + r32
    // hg chunk kc2 = by*8+wm*4+mt; octet = rq; u16 addr = rq*2048 + rr*8 + hi*4
    const float* b1e = b1 + (size_t)e * F_DIM + by * 256;
    #pragma unroll
    for (int mt = 0; mt < 4; ++mt) {
        const int kc2 = by * 8 + wm * 4 + mt;
        u16* hc = hg + ((size_t)bx * 96 + kc2) * 8192;
        #pragma unroll
        for (int rq = 0; rq < 4; ++rq) {
            const int floc = wm * 128 + mt * 32 + rq * 8 + hi * 4;
            const float4 bv = *(const float4*)&b1e[floc];
            #pragma unroll
            for (int nt = 0; nt < 4; ++nt) {
                const int rr = wn * 128 + nt * 32 + r32;
                const int e0 = rq * 4;
                uint2 pk;
                pk.x = cvt_pk_bf16(gelu_fast(acc[mt][nt][e0]     + bv.x),
                                   gelu_fast(acc[mt][nt][e0 + 1] + bv.y));
                pk.y = cvt_pk_bf16(gelu_fast(acc[mt][nt][e0 + 2] + bv.z),
                                   gelu_fast(acc[mt][nt][e0 + 3] + bv.w));
                *(uint2*)&hc[(size_t)rq * 2048 + (size_t)rr * 8 + hi * 4] = pk;
            }
        }
    }
}

// ---------------------------------------------------------------------------
// Stage 2: per (entry-tile256, d-tile256): C[m=d 256][n=entry 256], K=3072.
// 96 steps.  Epilogue: y[tokslot][d] = gate * C (bf16 stores, no atomics).
// ---------------------------------------------------------------------------
__global__ __launch_bounds__(256, 1) void s2_gemm(
    const u16* __restrict__ hg, const u16* __restrict__ w2g,
    const int* __restrict__ counts, const int* __restrict__ te,
    const int* __restrict__ tb, const int* __restrict__ ntile,
    const int* __restrict__ tokbuf, const float* __restrict__ gatebuf,
    u16* __restrict__ y)
{
    __shared__ __align__(16) u16 Als[3][8192];
    __shared__ __align__(16) u16 Bls[3][8192];
    __shared__ int   sts[256];
    __shared__ float sg[256];
    const int bx = blockIdx.x, by = blockIdx.y;   // by in [0,3): 256 d
    if (bx >= *ntile) return;
    const int e = te[bx], base = tb[bx], cnt = counts[e];
    const int NS_ = 96;

    const int tid  = threadIdx.x;
    const int w    = tid >> 6;
    const int lane = tid & 63;
    const int wm   = w & 1, wn = w >> 1;
    const int r32  = lane & 31, hi = lane >> 5;

    {
        const int ent = base + tid;
        const bool v = ent < cnt;
        sts[tid] = v ? tokbuf[(size_t)e * CAP + ent] : -1;
        sg[tid]  = v ? gatebuf[(size_t)e * CAP + ent] : 0.f;
    }
    // drain prefetch loads so the vmcnt ledger below is exact
    asm volatile("s_waitcnt vmcnt(0) lgkmcnt(0)" ::: "memory");
    bar_fenced();

    const u16* Ab = w2g + (size_t)(e * 3 + by) * 96 * 8192;
    const u16* Bb = hg  + (size_t)bx * 96 * 8192;

    f16v acc[4][4];
    #pragma unroll
    for (int mt = 0; mt < 4; ++mt)
        #pragma unroll
        for (int nt = 0; nt < 4; ++nt)
            #pragma unroll
            for (int ee = 0; ee < 16; ++ee) acc[mt][nt][ee] = 0.f;

    G_STAGE(0, 0);
    G_STAGE(1, 1);

    #pragma unroll 1
    for (int k = 0; k < 96; k += 3) {
        G_STEP(k,     0, 2);
        G_STEP(k + 1, 1, 0);
        G_STEP(k + 2, 2, 1);
    }
    wait_vmcnt<0>();

    // epilogue: d = by*256 + wm*128 + mt*32 + rq*8 + hi*4 + j
    //           entry rr = wn*128 + nt*32 + r32
    #pragma unroll
    for (int nt = 0; nt < 4; ++nt) {
        const int rr = wn * 128 + nt * 32 + r32;
        const int ts = sts[rr];
        if (ts >= 0) {
            const float g = sg[rr];
            u16* yr = y + (size_t)ts * D_DIM + by * 256 + wm * 128 + hi * 4;
            #pragma unroll
            for (int mt = 0; mt < 4; ++mt)
                #pragma unroll
                for (int rq = 0; rq < 4; ++rq) {
                    const int e0 = rq * 4;
                    uint2 pk;
                    pk.x = cvt_pk_bf16(g * acc[mt][nt][e0],
                                       g * acc[mt][nt][e0 + 1]);
                    pk.y = cvt_pk_bf16(g * acc[mt][nt][e0 + 2],
                                       g * acc[mt][nt][e0 + 3]);
                    *(uint2*)&yr[mt * 32 + rq * 8] = pk;
                }
        }
    }
}

// out = g0*b2[i0] + g1*b2[i1] + y[2t] + y[2t+1]
__global__ __launch_bounds__(256) void combine_kernel(
    const u16* __restrict__ y, const u32* __restrict__ rec_idx,
    const float2* __restrict__ rec_g, const float* __restrict__ b2,
    float* __restrict__ out)
{
    const int gid = blockIdx.x * 256 + threadIdx.x;
    const int t = gid / 192;
    const int c = (gid - t * 192) * 4;
    const u32 pk = rec_idx[t];
    const int i0 = pk & 15, i1 = (pk >> 4) & 15;
    const float2 g = rec_g[t];
    union { uint2 p; u16 u[4]; } a, b;
    a.p = *(const uint2*)&y[(size_t)(2 * t) * D_DIM + c];
    b.p = *(const uint2*)&y[(size_t)(2 * t + 1) * D_DIM + c];
    const float4 ba = *(const float4*)&b2[(size_t)i0 * D_DIM + c];
    const float4 bb = *(const float4*)&b2[(size_t)i1 * D_DIM + c];
    float4 o;
    o.x = g.x * ba.x + g.y * bb.x + bf2f(a.u[0]) + bf2f(b.u[0]);
    o.y = g.x * ba.y + g.y * bb.y + bf2f(a.u[1]) + bf2f(b.u[1]);
    o.z = g.x * ba.z + g.y * bb.z + bf2f(a.u[2]) + bf2f(b.u[2]);
    o.w = g.x * ba.w + g.y * bb.w + bf2f(a.u[3]) + bf2f(b.u[3]);
    *(float4*)&out[(size_t)t * D_DIM + c] = o;
}

// ---------------------------------------------------------------------------
extern "C" void kernel_launch(void* const* d_in, const int* in_sizes, int n_in,
                              void* d_out, int out_size, void* d_ws, size_t ws_size,
                              hipStream_t stream) {
    const float* x  = (const float*)d_in[0];
    const float* Wg = (const float*)d_in[1];
    const float* bg = (const float*)d_in[2];
    const float* W1 = (const float*)d_in[3];
    const float* b1 = (const float*)d_in[4];
    const float* W2 = (const float*)d_in[5];
    const float* b2 = (const float*)d_in[6];
    float* out = (float*)d_out;

    // ws layout (~243 MB)
    char* ws = (char*)d_ws;
    size_t off = 0;
    u16* xg  = (u16*)(ws + off); off += (size_t)NT2_MAX * 24 * 8192 * sizeof(u16);
    u16* w1g = (u16*)(ws + off); off += (size_t)E_EXP * F_DIM * D_DIM * sizeof(u16);
    u16* w2g = (u16*)(ws + off); off += (size_t)E_EXP * D_DIM * F_DIM * sizeof(u16);
    u16* hg  = (u16*)(ws + off); off += (size_t)NT2_MAX * 96 * 8192 * sizeof(u16);
    u16* y   = (u16*)(ws + off); off += (size_t)2 * N_TOK * D_DIM * sizeof(u16);
    int* tokbuf = (int*)(ws + off);      off += (size_t)E_EXP * CAP * sizeof(int);
    float* gatebuf = (float*)(ws + off); off += (size_t)E_EXP * CAP * sizeof(float);
    u32* rec_idx = (u32*)(ws + off);     off += (size_t)N_TOK * sizeof(u32);
    float2* rec_g = (float2*)(ws + off); off += (size_t)N_TOK * sizeof(float2);
    int* counts = (int*)(ws + off);      off += 64;
    int* te     = (int*)(ws + off);      off += NT2_MAX * sizeof(int);
    int* tb     = (int*)(ws + off);      off += NT2_MAX * sizeof(int);
    int* ntile  = (int*)(ws + off);      off += 64;

    prep_kernel<<<6656, 256, 0, stream>>>(x, Wg, bg, W1, W2, rec_idx, rec_g,
                                          w1g, w2g, counts);
    moe_scatter<<<N_TOK / 256, 256, 0, stream>>>(rec_idx, rec_g, counts, tokbuf, gatebuf);
    scan_kernel<<<1, 64, 0, stream>>>(counts, te, tb, ntile);
    pack_x<<<dim3(NT2_MAX * 2, 12), 256, 0, stream>>>(x, counts, te, tb, ntile,
                                                      tokbuf, xg);

    s1_gemm<<<dim3(NT2_MAX, 12), 256, 0, stream>>>(xg, w1g, b1, te, ntile, hg);
    s2_gemm<<<dim3(NT2_MAX, 3), 256, 0, stream>>>(hg, w2g, counts, te, tb, ntile,
                                                  tokbuf, gatebuf, y);
    combine_kernel<<<(N_TOK * 192) / 256, 256, 0, stream>>>(y, rec_idx, rec_g, b2, out);
}

// Round 10
// 526.076 us; speedup vs baseline: 1.1862x; 1.1749x over previous
//
#include <hip/hip_runtime.h>
#include <hip/hip_bf16.h>

// MoE: B=4,T=2048,D=768,E=8,F=3072,K=2.  N=8192 tokens, 16384 entries.
// Pipeline (7 launches):
//   prep      -> gates | pack W1 (256-row tiles) | pack W2 (256-row tiles)
//   scatter   -> buckets via wave-ballot aggregation
//   scan      -> tile table (expert, base) for <=136 entry-tiles
//   pack_x    -> gathered x as swizzled [128][32]-chunk tiles (s1 B operand)
//   s1        -> 256(f)x128(entry) GEMM, BK=32, 3-buf counted-vmcnt,
//                m201-style 2-phase interleave per K-step
//   s2        -> 256(d)x128(entry) GEMM, same schedule, 96 K-steps
//   combine   -> out = g0*b2[i0] + g1*b2[i1] + y[2t] + y[2t+1]

#define N_TOK 8192
#define D_DIM 768
#define E_EXP 8
#define F_DIM 3072
#define CAP   8192
#define NT_MAX 136          // max entry tiles: 16384/128 + 8 ceil slack

typedef __attribute__((ext_vector_type(8))) short s8v;   // 8 x bf16
typedef __attribute__((ext_vector_type(4))) float f4v;   // MFMA acc
typedef unsigned short u16;
typedef unsigned int   u32;
typedef unsigned long long u64;

static __device__ __forceinline__ u16 f2bf(float f) {
    u32 u = __float_as_uint(f);
    return (u16)((u + 0x7fffu + ((u >> 16) & 1u)) >> 16);   // RNE
}
static __device__ __forceinline__ float bf2f(u16 v) {
    return __uint_as_float((u32)v << 16);
}
// pack two f32 -> two bf16 (RNE) in one instruction
static __device__ __forceinline__ u32 cvt_pk_bf16(float lo, float hi) {
    u32 r;
    asm("v_cvt_pk_bf16_f32 %0, %1, %2" : "=v"(r) : "v"(lo), "v"(hi));
    return r;
}
// Branch-free erf-based GELU (A&S 7.1.26, |eps_erf| <= 1.5e-7).
static __device__ __forceinline__ float gelu_fast(float v) {
    const float av = fabsf(v);
    const float z  = av * 0.70710678118654752440f;
    const float t  = __builtin_amdgcn_rcpf(fmaf(0.3275911f, z, 1.0f));
    const float w  = __builtin_amdgcn_exp2f(-z * z * 1.4426950408889634f);
    float p = fmaf(1.061405429f, t, -1.453152027f);
    p = fmaf(p, t,  1.421413741f);
    p = fmaf(p, t, -0.284496736f);
    p = fmaf(p, t,  0.254829592f);
    p = p * t;
    const float E = 1.0f - p * w;       // erf(z), z >= 0
    return 0.5f * (v + av * E);
}
static __device__ __forceinline__ void gld_lds16(const u16* g, u16* l) {
    __builtin_amdgcn_global_load_lds(
        (const __attribute__((address_space(1))) void*)g,
        (__attribute__((address_space(3))) void*)l, 16, 0, 0);
}
template<int N> static __device__ __forceinline__ void wait_vmcnt() {
    asm volatile("s_waitcnt vmcnt(%0)" :: "n"(N) : "memory");
}
static __device__ __forceinline__ void wait_lgkm0() {
    asm volatile("s_waitcnt lgkmcnt(0)" ::: "memory");
    __builtin_amdgcn_sched_barrier(0);
}
// asm barrier = HW barrier + compiler memory fence.
static __device__ __forceinline__ void bar_fenced() {
    asm volatile("s_barrier" ::: "memory");
}

// ---------------------------------------------------------------------------
// Fused prep: block ranges do independent jobs.
//   [0,2048)      gates: 4 tokens/block (wave per token)
//   [2048,4352)   pack W1 -> w1g, 256-row tiles, 32-col chunks (KC2=24)
//   [4352,6656)   pack W2 -> w2g, 256-row tiles, 32-col chunks (KC2=96)
//   block 0 also zeros counts.
// Packed chunk layout (LDS image): [row][32 cols], col-group cg (4 x 8)
// stored at physical group (cg ^ ((row>>1)&3)) -> conflict-free ds_read_b128.
// ---------------------------------------------------------------------------
__device__ __forceinline__ void pack_w_body(
    const float* __restrict__ src, u16* __restrict__ dst,
    int rt, int kc64, int e, int K1, int M2, int KC2, int TR, int ntm)
{
    __shared__ float ls[64][132];
    const float* se = src + (size_t)e * K1 * M2;
    const int tid = threadIdx.x;

    const int kr = tid >> 2, mq = tid & 3;
    const float* srow = se + (size_t)(kc64 * 64 + kr) * M2 + rt * 128 + mq * 32;
    #pragma unroll
    for (int it = 0; it < 8; ++it)
        *(float4*)&ls[kr][mq * 32 + it * 4] = *(const float4*)(srow + it * 4);
    __syncthreads();

    // two 32-col chunks: kc64*2 + hf
    u16* dt_ = dst + ((size_t)(e * ntm + (rt * 128) / TR) * KC2 + kc64 * 2)
                     * ((size_t)TR * 32)
                   + (size_t)((rt * 128) % TR) * 32;
    const int rr = tid >> 1, hf = tid & 1;
    u16* dc = dt_ + (size_t)hf * TR * 32;
    const int row = ((rt * 128) % TR) + rr;
    #pragma unroll
    for (int j = 0; j < 4; ++j) {
        union { s8v v; u16 u[8]; } o;
        #pragma unroll
        for (int jj = 0; jj < 8; ++jj)
            o.u[jj] = f2bf(ls[hf * 32 + j * 8 + jj][rr]);
        *(s8v*)&dc[(size_t)rr * 32 + ((j ^ ((row >> 1) & 3)) * 8)] = o.v;
    }
}

__global__ __launch_bounds__(256) void prep_kernel(
    const float* __restrict__ x, const float* __restrict__ Wg,
    const float* __restrict__ bg, const float* __restrict__ W1,
    const float* __restrict__ W2, u32* __restrict__ rec_idx,
    float2* __restrict__ rec_g, u16* __restrict__ w1g,
    u16* __restrict__ w2g, int* __restrict__ counts)
{
    const int bid = blockIdx.x;
    if (bid == 0 && threadIdx.x < E_EXP) counts[threadIdx.x] = 0;

    if (bid < 2048) {
        // ------- gates -------
        const int wave = threadIdx.x >> 6;
        const int lane = threadIdx.x & 63;
        const int t = bid * 4 + wave;

        float acc[8];
        #pragma unroll
        for (int e = 0; e < 8; ++e) acc[e] = 0.f;

        const float* xrow = x + (size_t)t * D_DIM + lane * 12;
        #pragma unroll
        for (int i = 0; i < 3; ++i) {
            float4 xv = *(const float4*)(xrow + i * 4);
            float xs[4] = {xv.x, xv.y, xv.z, xv.w};
            #pragma unroll
            for (int j = 0; j < 4; ++j) {
                const int d = lane * 12 + i * 4 + j;
                const float4 w0 = *(const float4*)(Wg + (size_t)d * 8);
                const float4 w1 = *(const float4*)(Wg + (size_t)d * 8 + 4);
                acc[0] += xs[j] * w0.x;  acc[1] += xs[j] * w0.y;
                acc[2] += xs[j] * w0.z;  acc[3] += xs[j] * w0.w;
                acc[4] += xs[j] * w1.x;  acc[5] += xs[j] * w1.y;
                acc[6] += xs[j] * w1.z;  acc[7] += xs[j] * w1.w;
            }
        }
        #pragma unroll
        for (int e = 0; e < 8; ++e) {
            float v = acc[e];
            #pragma unroll
            for (int off = 32; off > 0; off >>= 1) v += __shfl_xor(v, off, 64);
            acc[e] = v + bg[e];
        }
        if (lane == 0) {
            float mx = acc[0];
            #pragma unroll
            for (int e = 1; e < 8; ++e) mx = fmaxf(mx, acc[e]);
            float p[8], s = 0.f;
            #pragma unroll
            for (int e = 0; e < 8; ++e) { p[e] = expf(acc[e] - mx); s += p[e]; }
            const float inv = 1.f / s;
            #pragma unroll
            for (int e = 0; e < 8; ++e) p[e] *= inv;

            int i0 = 0; float g0 = p[0];
            #pragma unroll
            for (int e = 1; e < 8; ++e) if (p[e] > g0) { g0 = p[e]; i0 = e; }
            int i1 = -1; float g1 = -1.f;
            #pragma unroll
            for (int e = 0; e < 8; ++e) if (e != i0 && p[e] > g1) { g1 = p[e]; i1 = e; }

            rec_idx[t] = (u32)i0 | ((u32)i1 << 4);
            rec_g[t] = make_float2(g0, g1);
        }
    } else if (bid < 4352) {
        // ------- pack W1: [E][768][3072] -> 256-row tiles, KC2=24 -------
        const int id = bid - 2048;               // e*288 + rt*12 + kc64
        const int e = id / 288, rem = id - e * 288;
        const int rt = rem / 12, kc = rem - rt * 12;
        pack_w_body(W1, w1g, rt, kc, e, D_DIM, F_DIM, 24, 256, 12);
    } else {
        // ------- pack W2: [E][3072][768] -> 256-row tiles, KC2=96 -------
        const int id = bid - 4352;               // e*288 + rt*48 + kc64
        const int e = id / 288, rem = id - e * 288;
        const int rt = rem / 48, kc = rem - rt * 48;
        pack_w_body(W2, w2g, rt, kc, e, F_DIM, D_DIM, 96, 256, 3);
    }
}

// ---------------------------------------------------------------------------
// Scatter: thread per token, wave-ballot aggregation -> <=8 atomics/wave.
// ---------------------------------------------------------------------------
__global__ __launch_bounds__(256) void moe_scatter(
    const u32* __restrict__ rec_idx, const float2* __restrict__ rec_g,
    int* __restrict__ counts, int* __restrict__ tokbuf,
    float* __restrict__ gatebuf)
{
    const int t = blockIdx.x * 256 + threadIdx.x;
    const int lane = threadIdx.x & 63;
    const u32 pk = rec_idx[t];
    const int i0 = pk & 15, i1 = (pk >> 4) & 15;
    const float2 g = rec_g[t];
    const u64 lmask = ((u64)1 << lane) - 1;

    #pragma unroll
    for (int e = 0; e < 8; ++e) {
        const u64 m0 = __ballot(i0 == e);
        const u64 m1 = __ballot(i1 == e);
        const int c0 = __popcll(m0);
        const int total = c0 + __popcll(m1);
        if (total > 0) {
            int base = 0;
            if (lane == 0) base = atomicAdd(&counts[e], total);
            base = __shfl(base, 0, 64);
            if (i0 == e) {
                const int p = base + __popcll(m0 & lmask);
                tokbuf[(size_t)e * CAP + p] = 2 * t;
                gatebuf[(size_t)e * CAP + p] = g.x;
            }
            if (i1 == e) {
                const int p = base + c0 + __popcll(m1 & lmask);
                tokbuf[(size_t)e * CAP + p] = 2 * t + 1;
                gatebuf[(size_t)e * CAP + p] = g.y;
            }
        }
    }
}

// tile table: for each expert, one tile per 128 entries
__global__ void scan_kernel(const int* __restrict__ counts,
                            int* __restrict__ te, int* __restrict__ tb,
                            int* __restrict__ ntile) {
    if (threadIdx.x == 0) {
        int nt = 0;
        for (int e = 0; e < E_EXP; ++e)
            for (int k = 0; k * 128 < counts[e]; ++k) {
                te[nt] = e; tb[nt] = k * 128; ++nt;
            }
        *ntile = nt;
    }
}

// ---------------------------------------------------------------------------
// pack_x: gather token rows -> swizzled bf16 [128][32]-chunk tiles.
// grid (NT_MAX, 12): block handles 64 d-cols = chunks kc*2, kc*2+1.
// ---------------------------------------------------------------------------
__global__ __launch_bounds__(256) void pack_x(
    const float* __restrict__ x, const int* __restrict__ counts,
    const int* __restrict__ te, const int* __restrict__ tb,
    const int* __restrict__ ntile, const int* __restrict__ tokbuf,
    u16* __restrict__ xg)
{
    const int bx = blockIdx.x, kc = blockIdx.y;
    if (bx >= *ntile) return;
    const int e = te[bx], base = tb[bx], cnt = counts[e];
    const int tid = threadIdx.x;
    const int r = tid >> 1, hf = tid & 1;
    int ent = base + r; if (ent >= cnt) ent = cnt - 1;
    const int tok = tokbuf[(size_t)e * CAP + ent] >> 1;
    const float* xr = x + (size_t)tok * D_DIM + kc * 64 + hf * 32;
    u16* xt = xg + ((size_t)bx * 24 + kc * 2 + hf) * 4096;
    #pragma unroll
    for (int j = 0; j < 4; ++j) {
        float4 a = *(const float4*)(xr + j * 8);
        float4 b = *(const float4*)(xr + j * 8 + 4);
        union { s8v v; u16 u[8]; } o;
        o.u[0] = f2bf(a.x); o.u[1] = f2bf(a.y); o.u[2] = f2bf(a.z); o.u[3] = f2bf(a.w);
        o.u[4] = f2bf(b.x); o.u[5] = f2bf(b.y); o.u[6] = f2bf(b.z); o.u[7] = f2bf(b.w);
        *(s8v*)&xt[(size_t)r * 32 + ((j ^ ((r >> 1) & 3)) * 8)] = o.v;
    }
}

// ---------------------------------------------------------------------------
// Shared GEMM step: 256(m)x128(n) block, 4 waves of 128x64, BK=32.
// Triple-buffered counted-vmcnt + m201-style 2-PHASE interleave per step:
//   phase0: read af[0..3]+bf[0..3] | stage half(S+2) | bar | lgkm0 |
//           setprio 16 MFMA (mi 0-3) | bar
//   phase1: read af[4..7] (bf held) | stage half(S+2) | bar | lgkm0 |
//           setprio 16 MFMA (mi 4-7) |
//   step end: vmcnt(6) [buf S+1 complete] | bar  -> publishes next buffer.
// vmcnt never drains to 0 in the main loop (2 stages in flight).
// Tail stages clamp to the last K-step (uniform ledger, in-bounds).
// LDS: 3 x (16KB A + 8KB B) = 72KB -> 2 blocks/CU.
// ---------------------------------------------------------------------------
#define G_STAGE(S, SBUF) do {                                                 \
    const int S__ = (S) < NS_ ? (S) : NS_ - 1;                                \
    const u16* An_ = Ab + (size_t)S__ * 8192 + w * 2048 + lane * 8;           \
    const u16* Bn_ = Bb + (size_t)S__ * 4096 + w * 1024 + lane * 8;           \
    u16* Ad_ = &Als[SBUF][w * 2048];                                          \
    u16* Bd_ = &Bls[SBUF][w * 1024];                                          \
    gld_lds16(An_,        Ad_);                                               \
    gld_lds16(An_ +  512, Ad_ +  512);                                        \
    gld_lds16(An_ + 1024, Ad_ + 1024);                                        \
    gld_lds16(An_ + 1536, Ad_ + 1536);                                        \
    gld_lds16(Bn_,        Bd_);                                               \
    gld_lds16(Bn_ +  512, Bd_ +  512);                                        \
} while (0)

#define G_STAGE_H0(S, SBUF) do {                                              \
    const int S__ = (S) < NS_ ? (S) : NS_ - 1;                                \
    const u16* An_ = Ab + (size_t)S__ * 8192 + w * 2048 + lane * 8;           \
    const u16* Bn_ = Bb + (size_t)S__ * 4096 + w * 1024 + lane * 8;           \
    gld_lds16(An_,       &Als[SBUF][w * 2048]);                               \
    gld_lds16(An_ + 512, &Als[SBUF][w * 2048 + 512]);                         \
    gld_lds16(Bn_,       &Bls[SBUF][w * 1024]);                               \
} while (0)

#define G_STAGE_H1(S, SBUF) do {                                              \
    const int S__ = (S) < NS_ ? (S) : NS_ - 1;                                \
    const u16* An_ = Ab + (size_t)S__ * 8192 + w * 2048 + lane * 8;           \
    const u16* Bn_ = Bb + (size_t)S__ * 4096 + w * 1024 + lane * 8;           \
    gld_lds16(An_ + 1024, &Als[SBUF][w * 2048 + 1024]);                       \
    gld_lds16(An_ + 1536, &Als[SBUF][w * 2048 + 1536]);                       \
    gld_lds16(Bn_ + 512,  &Bls[SBUF][w * 1024 + 512]);                        \
} while (0)

#define G_STEP(S, BUF, B2) do {                                               \
    s8v af[4], bf[4];                                                         \
    _Pragma("unroll")                                                         \
    for (int mi = 0; mi < 4; ++mi)                                            \
        af[mi] = *(const s8v*)&Als[BUF][(wm*128 + mi*16 + ln)*32 + colU];     \
    _Pragma("unroll")                                                         \
    for (int ni = 0; ni < 4; ++ni)                                            \
        bf[ni] = *(const s8v*)&Bls[BUF][(wn*64 + ni*16 + ln)*32 + colU];      \
    G_STAGE_H0((S) + 2, B2);                                                  \
    bar_fenced();                                                             \
    wait_lgkm0();                                                             \
    __builtin_amdgcn_s_setprio(1);                                            \
    _Pragma("unroll")                                                         \
    for (int mi = 0; mi < 4; ++mi)                                            \
        _Pragma("unroll")                                                     \
        for (int ni = 0; ni < 4; ++ni)                                        \
            acc[mi][ni] = __builtin_amdgcn_mfma_f32_16x16x32_bf16(            \
                af[mi], bf[ni], acc[mi][ni], 0, 0, 0);                        \
    __builtin_amdgcn_s_setprio(0);                                            \
    bar_fenced();                                                             \
    _Pragma("unroll")                                                         \
    for (int mi = 0; mi < 4; ++mi)                                            \
        af[mi] = *(const s8v*)&Als[BUF][(wm*128 + (mi+4)*16 + ln)*32 + colU]; \
    G_STAGE_H1((S) + 2, B2);                                                  \
    bar_fenced();                                                             \
    wait_lgkm0();                                                             \
    __builtin_amdgcn_s_setprio(1);                                            \
    _Pragma("unroll")                                                         \
    for (int mi = 0; mi < 4; ++mi)                                            \
        _Pragma("unroll")                                                     \
        for (int ni = 0; ni < 4; ++ni)                                        \
            acc[4 + mi][ni] = __builtin_amdgcn_mfma_f32_16x16x32_bf16(        \
                af[mi], bf[ni], acc[4 + mi][ni], 0, 0, 0);                    \
    __builtin_amdgcn_s_setprio(0);                                            \
    wait_vmcnt<6>();                                                          \
    bar_fenced();                                                             \
} while (0)

// ---------------------------------------------------------------------------
// Stage 1: per (entry-tile, f-tile256): C[m=f 256][n=entry 128], K=768.
// 24 steps.  Epilogue: bias + fast-erf GELU -> bf16 hg in s2-B 32-col layout.
// ---------------------------------------------------------------------------
__global__ __launch_bounds__(256, 2) void s1_gemm(
    const u16* __restrict__ xg, const u16* __restrict__ w1g,
    const float* __restrict__ b1, const int* __restrict__ te,
    const int* __restrict__ ntile, u16* __restrict__ hg)
{
    __shared__ __align__(16) u16 Als[3][8192];   // 256 rows x 32 per buf
    __shared__ __align__(16) u16 Bls[3][4096];   // 128 rows x 32 per buf
    const int bx = blockIdx.x, by = blockIdx.y;   // by in [0,12): 256 f
    if (bx >= *ntile) return;
    const int e = te[bx];
    const int NS_ = 24;

    const int tid  = threadIdx.x;
    const int w    = tid >> 6;
    const int lane = tid & 63;
    const int wm   = w & 1, wn = w >> 1;
    const int q    = lane >> 4, ln = lane & 15;
    const int colU = (q ^ ((ln >> 1) & 3)) * 8;

    const u16* Ab = w1g + (size_t)(e * 12 + by) * 24 * 8192;
    const u16* Bb = xg  + (size_t)bx * 24 * 4096;

    f4v acc[8][4];
    #pragma unroll
    for (int mi = 0; mi < 8; ++mi)
        #pragma unroll
        for (int ni = 0; ni < 4; ++ni) acc[mi][ni] = (f4v){0.f,0.f,0.f,0.f};

    // prologue: 2 stages in flight; publish buf 0
    G_STAGE(0, 0);
    G_STAGE(1, 1);
    wait_vmcnt<6>();
    bar_fenced();

    #pragma unroll 1
    for (int k = 0; k < 24; k += 3) {
        G_STEP(k,     0, 2);
        G_STEP(k + 1, 1, 0);
        G_STEP(k + 2, 2, 1);
    }
    wait_vmcnt<0>();

    // epilogue: f_local = wm*128 + mi*16 + q*4 (+r), entry = wn*64 + ni*16 + ln
    const float* b1e = b1 + (size_t)e * F_DIM + by * 256;
    #pragma unroll
    for (int mi = 0; mi < 8; ++mi) {
        const int floc = wm * 128 + mi * 16 + q * 4;
        const int kc2  = by * 8 + (floc >> 5);       // 32-f chunk index
        const int cg   = (floc >> 3) & 3;            // col-group within chunk
        const float4 bv = *(const float4*)&b1e[floc];
        #pragma unroll
        for (int ni = 0; ni < 4; ++ni) {
            const int rr = wn * 64 + ni * 16 + ln;
            uint2 pk;
            pk.x = cvt_pk_bf16(gelu_fast(acc[mi][ni][0] + bv.x),
                               gelu_fast(acc[mi][ni][1] + bv.y));
            pk.y = cvt_pk_bf16(gelu_fast(acc[mi][ni][2] + bv.z),
                               gelu_fast(acc[mi][ni][3] + bv.w));
            *(uint2*)&hg[((size_t)bx * 96 + kc2) * 4096 +
                         (size_t)rr * 32 + ((cg ^ ((rr >> 1) & 3)) * 8) +
                         (q & 1) * 4] = pk;
        }
    }
}

// ---------------------------------------------------------------------------
// Stage 2: per (entry-tile, d-tile256): C[m=d 256][n=entry 128], K=3072.
// 96 steps, same geometry/schedule as s1 (by in [0,3)).
// Epilogue: y[tokslot][d] = gate * C  (bf16 stores, no atomics).
// ---------------------------------------------------------------------------
__global__ __launch_bounds__(256, 2) void s2_gemm(
    const u16* __restrict__ hg, const u16* __restrict__ w2g,
    const int* __restrict__ counts, const int* __restrict__ te,
    const int* __restrict__ tb, const int* __restrict__ ntile,
    const int* __restrict__ tokbuf, const float* __restrict__ gatebuf,
    u16* __restrict__ y)
{
    __shared__ __align__(16) u16 Als[3][8192];   // 256 rows x 32 per buf
    __shared__ __align__(16) u16 Bls[3][4096];   // 128 rows x 32 per buf
    __shared__ int   sts[128];
    __shared__ float sg[128];
    const int bx = blockIdx.x, by = blockIdx.y;   // by in [0,3): 256 d
    if (bx >= *ntile) return;
    const int e = te[bx], base = tb[bx], cnt = counts[e];
    const int NS_ = 96;

    const int tid  = threadIdx.x;
    const int w    = tid >> 6;
    const int lane = tid & 63;
    const int wm   = w & 1, wn = w >> 1;
    const int q    = lane >> 4, ln = lane & 15;
    const int colU = (q ^ ((ln >> 1) & 3)) * 8;

    if (tid < 128) {
        const int ent = base + tid;
        const bool v = ent < cnt;
        sts[tid] = v ? tokbuf[(size_t)e * CAP + ent] : -1;
        sg[tid]  = v ? gatebuf[(size_t)e * CAP + ent] : 0.f;
    }
    // drain the prefetch loads so the vmcnt ledger below is exact
    asm volatile("s_waitcnt vmcnt(0) lgkmcnt(0)" ::: "memory");
    bar_fenced();

    const u16* Ab = w2g + (size_t)(e * 3 + by) * 96 * 8192;
    const u16* Bb = hg  + (size_t)bx * 96 * 4096;

    f4v acc[8][4];
    #pragma unroll
    for (int mi = 0; mi < 8; ++mi)
        #pragma unroll
        for (int ni = 0; ni < 4; ++ni) acc[mi][ni] = (f4v){0.f,0.f,0.f,0.f};

    G_STAGE(0, 0);
    G_STAGE(1, 1);
    wait_vmcnt<6>();
    bar_fenced();

    #pragma unroll 1
    for (int k = 0; k < 96; k += 3) {
        G_STEP(k,     0, 2);
        G_STEP(k + 1, 1, 0);
        G_STEP(k + 2, 2, 1);
    }
    wait_vmcnt<0>();

    // epilogue: d = by*256 + wm*128 + mi*16 + q*4, entry = wn*64 + ni*16 + ln
    #pragma unroll
    for (int ni = 0; ni < 4; ++ni) {
        const int rr = wn * 64 + ni * 16 + ln;
        const int ts = sts[rr];
        if (ts >= 0) {
            const float g = sg[rr];
            u16* yr = y + (size_t)ts * D_DIM + by * 256 + wm * 128 + q * 4;
            #pragma unroll
            for (int mi = 0; mi < 8; ++mi) {
                uint2 pk;
                pk.x = cvt_pk_bf16(g * acc[mi][ni][0], g * acc[mi][ni][1]);
                pk.y = cvt_pk_bf16(g * acc[mi][ni][2], g * acc[mi][ni][3]);
                *(uint2*)&yr[mi * 16] = pk;
            }
        }
    }
}

// out = g0*b2[i0] + g1*b2[i1] + y[2t] + y[2t+1]
__global__ __launch_bounds__(256) void combine_kernel(
    const u16* __restrict__ y, const u32* __restrict__ rec_idx,
    const float2* __restrict__ rec_g, const float* __restrict__ b2,
    float* __restrict__ out)
{
    const int gid = blockIdx.x * 256 + threadIdx.x;
    const int t = gid / 192;
    const int c = (gid - t * 192) * 4;
    const u32 pk = rec_idx[t];
    const int i0 = pk & 15, i1 = (pk >> 4) & 15;
    const float2 g = rec_g[t];
    union { uint2 p; u16 u[4]; } a, b;
    a.p = *(const uint2*)&y[(size_t)(2 * t) * D_DIM + c];
    b.p = *(const uint2*)&y[(size_t)(2 * t + 1) * D_DIM + c];
    const float4 ba = *(const float4*)&b2[(size_t)i0 * D_DIM + c];
    const float4 bb = *(const float4*)&b2[(size_t)i1 * D_DIM + c];
    float4 o;
    o.x = g.x * ba.x + g.y * bb.x + bf2f(a.u[0]) + bf2f(b.u[0]);
    o.y = g.x * ba.y + g.y * bb.y + bf2f(a.u[1]) + bf2f(b.u[1]);
    o.z = g.x * ba.z + g.y * bb.z + bf2f(a.u[2]) + bf2f(b.u[2]);
    o.w = g.x * ba.w + g.y * bb.w + bf2f(a.u[3]) + bf2f(b.u[3]);
    *(float4*)&out[(size_t)t * D_DIM + c] = o;
}

// ---------------------------------------------------------------------------
extern "C" void kernel_launch(void* const* d_in, const int* in_sizes, int n_in,
                              void* d_out, int out_size, void* d_ws, size_t ws_size,
                              hipStream_t stream) {
    const float* x  = (const float*)d_in[0];
    const float* Wg = (const float*)d_in[1];
    const float* bg = (const float*)d_in[2];
    const float* W1 = (const float*)d_in[3];
    const float* b1 = (const float*)d_in[4];
    const float* W2 = (const float*)d_in[5];
    const float* b2 = (const float*)d_in[6];
    float* out = (float*)d_out;

    // ws layout (~235 MB)
    char* ws = (char*)d_ws;
    size_t off = 0;
    u16* xg  = (u16*)(ws + off); off += (size_t)NT_MAX * 24 * 4096 * sizeof(u16);
    u16* w1g = (u16*)(ws + off); off += (size_t)E_EXP * F_DIM * D_DIM * sizeof(u16);
    u16* w2g = (u16*)(ws + off); off += (size_t)E_EXP * D_DIM * F_DIM * sizeof(u16);
    u16* hg  = (u16*)(ws + off); off += (size_t)NT_MAX * 96 * 4096 * sizeof(u16);
    u16* y   = (u16*)(ws + off); off += (size_t)2 * N_TOK * D_DIM * sizeof(u16);
    int* tokbuf = (int*)(ws + off);      off += (size_t)E_EXP * CAP * sizeof(int);
    float* gatebuf = (float*)(ws + off); off += (size_t)E_EXP * CAP * sizeof(float);
    u32* rec_idx = (u32*)(ws + off);     off += (size_t)N_TOK * sizeof(u32);
    float2* rec_g = (float2*)(ws + off); off += (size_t)N_TOK * sizeof(float2);
    int* counts = (int*)(ws + off);      off += 64;
    int* te     = (int*)(ws + off);      off += NT_MAX * sizeof(int);
    int* tb     = (int*)(ws + off);      off += NT_MAX * sizeof(int);
    int* ntile  = (int*)(ws + off);      off += 64;

    prep_kernel<<<6656, 256, 0, stream>>>(x, Wg, bg, W1, W2, rec_idx, rec_g,
                                          w1g, w2g, counts);
    moe_scatter<<<N_TOK / 256, 256, 0, stream>>>(rec_idx, rec_g, counts, tokbuf, gatebuf);
    scan_kernel<<<1, 64, 0, stream>>>(counts, te, tb, ntile);
    pack_x<<<dim3(NT_MAX, 12), 256, 0, stream>>>(x, counts, te, tb, ntile, tokbuf, xg);

    s1_gemm<<<dim3(NT_MAX, 12), 256, 0, stream>>>(xg, w1g, b1, te, ntile, hg);
    s2_gemm<<<dim3(NT_MAX, 3), 256, 0, stream>>>(hg, w2g, counts, te, tb, ntile,
                                                 tokbuf, gatebuf, y);
    combine_kernel<<<(N_TOK * 192) / 256, 256, 0, stream>>>(y, rec_idx, rec_g, b2, out);
}

// Round 11
// 492.072 us; speedup vs baseline: 1.2682x; 1.0691x over previous
//
#include <hip/hip_runtime.h>
#include <hip/hip_bf16.h>

// MoE: B=4,T=2048,D=768,E=8,F=3072,K=2.  N=8192 tokens, 16384 entries.
// Pipeline (7 launches):
//   prep      -> gates | pack W1 (256-row tiles) | pack W2 (256-row tiles)
//   scatter   -> buckets via wave-ballot aggregation
//   scan      -> tile table (expert, base) for <=136 entry-tiles
//   pack_x    -> gathered x as swizzled [128][32]-chunk tiles (s1 B operand)
//   s1        -> 256(f)x128(entry) GEMM, BK=32, 3-buf counted-vmcnt,
//                XCD-chunked block mapping (17 bx-tiles per XCD)
//   s2        -> 256(d)x128(entry) GEMM, same schedule, 96 K-steps
//   combine   -> out = g0*b2[i0] + g1*b2[i1] + y[2t] + y[2t+1]

#define N_TOK 8192
#define D_DIM 768
#define E_EXP 8
#define F_DIM 3072
#define CAP   8192
#define NT_MAX 136          // max entry tiles: 16384/128 + 8 ceil slack (8*17)

typedef __attribute__((ext_vector_type(8))) short s8v;   // 8 x bf16
typedef __attribute__((ext_vector_type(4))) float f4v;   // MFMA acc
typedef unsigned short u16;
typedef unsigned int   u32;
typedef unsigned long long u64;

static __device__ __forceinline__ u16 f2bf(float f) {
    u32 u = __float_as_uint(f);
    return (u16)((u + 0x7fffu + ((u >> 16) & 1u)) >> 16);   // RNE
}
static __device__ __forceinline__ float bf2f(u16 v) {
    return __uint_as_float((u32)v << 16);
}
// pack two f32 -> two bf16 (RNE) in one instruction
static __device__ __forceinline__ u32 cvt_pk_bf16(float lo, float hi) {
    u32 r;
    asm("v_cvt_pk_bf16_f32 %0, %1, %2" : "=v"(r) : "v"(lo), "v"(hi));
    return r;
}
// Branch-free erf-based GELU (A&S 7.1.26, |eps_erf| <= 1.5e-7).
static __device__ __forceinline__ float gelu_fast(float v) {
    const float av = fabsf(v);
    const float z  = av * 0.70710678118654752440f;
    const float t  = __builtin_amdgcn_rcpf(fmaf(0.3275911f, z, 1.0f));
    const float w  = __builtin_amdgcn_exp2f(-z * z * 1.4426950408889634f);
    float p = fmaf(1.061405429f, t, -1.453152027f);
    p = fmaf(p, t,  1.421413741f);
    p = fmaf(p, t, -0.284496736f);
    p = fmaf(p, t,  0.254829592f);
    p = p * t;
    const float E = 1.0f - p * w;       // erf(z), z >= 0
    return 0.5f * (v + av * E);
}
static __device__ __forceinline__ void gld_lds16(const u16* g, u16* l) {
    __builtin_amdgcn_global_load_lds(
        (const __attribute__((address_space(1))) void*)g,
        (__attribute__((address_space(3))) void*)l, 16, 0, 0);
}
template<int N> static __device__ __forceinline__ void wait_vmcnt() {
    asm volatile("s_waitcnt vmcnt(%0)" :: "n"(N) : "memory");
}
// asm barrier = HW barrier + compiler memory fence.
static __device__ __forceinline__ void bar_fenced() {
    asm volatile("s_barrier" ::: "memory");
}

// ---------------------------------------------------------------------------
// Fused prep: block ranges do independent jobs.
//   [0,2048)      gates: 4 tokens/block (wave per token)
//   [2048,4352)   pack W1 -> w1g, 256-row tiles, 32-col chunks (KC2=24)
//   [4352,6656)   pack W2 -> w2g, 256-row tiles, 32-col chunks (KC2=96)
//   block 0 also zeros counts.
// Packed chunk layout (LDS image): [row][32 cols], col-group cg (4 x 8)
// stored at physical group (cg ^ ((row>>1)&3)) -> conflict-free ds_read_b128.
// ---------------------------------------------------------------------------
__device__ __forceinline__ void pack_w_body(
    const float* __restrict__ src, u16* __restrict__ dst,
    int rt, int kc64, int e, int K1, int M2, int KC2, int TR, int ntm)
{
    __shared__ float ls[64][132];
    const float* se = src + (size_t)e * K1 * M2;
    const int tid = threadIdx.x;

    const int kr = tid >> 2, mq = tid & 3;
    const float* srow = se + (size_t)(kc64 * 64 + kr) * M2 + rt * 128 + mq * 32;
    #pragma unroll
    for (int it = 0; it < 8; ++it)
        *(float4*)&ls[kr][mq * 32 + it * 4] = *(const float4*)(srow + it * 4);
    __syncthreads();

    // two 32-col chunks: kc64*2 + hf
    u16* dt_ = dst + ((size_t)(e * ntm + (rt * 128) / TR) * KC2 + kc64 * 2)
                     * ((size_t)TR * 32)
                   + (size_t)((rt * 128) % TR) * 32;
    const int rr = tid >> 1, hf = tid & 1;
    u16* dc = dt_ + (size_t)hf * TR * 32;
    const int row = ((rt * 128) % TR) + rr;
    #pragma unroll
    for (int j = 0; j < 4; ++j) {
        union { s8v v; u16 u[8]; } o;
        #pragma unroll
        for (int jj = 0; jj < 8; ++jj)
            o.u[jj] = f2bf(ls[hf * 32 + j * 8 + jj][rr]);
        *(s8v*)&dc[(size_t)rr * 32 + ((j ^ ((row >> 1) & 3)) * 8)] = o.v;
    }
}

__global__ __launch_bounds__(256) void prep_kernel(
    const float* __restrict__ x, const float* __restrict__ Wg,
    const float* __restrict__ bg, const float* __restrict__ W1,
    const float* __restrict__ W2, u32* __restrict__ rec_idx,
    float2* __restrict__ rec_g, u16* __restrict__ w1g,
    u16* __restrict__ w2g, int* __restrict__ counts)
{
    const int bid = blockIdx.x;
    if (bid == 0 && threadIdx.x < E_EXP) counts[threadIdx.x] = 0;

    if (bid < 2048) {
        // ------- gates -------
        const int wave = threadIdx.x >> 6;
        const int lane = threadIdx.x & 63;
        const int t = bid * 4 + wave;

        float acc[8];
        #pragma unroll
        for (int e = 0; e < 8; ++e) acc[e] = 0.f;

        const float* xrow = x + (size_t)t * D_DIM + lane * 12;
        #pragma unroll
        for (int i = 0; i < 3; ++i) {
            float4 xv = *(const float4*)(xrow + i * 4);
            float xs[4] = {xv.x, xv.y, xv.z, xv.w};
            #pragma unroll
            for (int j = 0; j < 4; ++j) {
                const int d = lane * 12 + i * 4 + j;
                const float4 w0 = *(const float4*)(Wg + (size_t)d * 8);
                const float4 w1 = *(const float4*)(Wg + (size_t)d * 8 + 4);
                acc[0] += xs[j] * w0.x;  acc[1] += xs[j] * w0.y;
                acc[2] += xs[j] * w0.z;  acc[3] += xs[j] * w0.w;
                acc[4] += xs[j] * w1.x;  acc[5] += xs[j] * w1.y;
                acc[6] += xs[j] * w1.z;  acc[7] += xs[j] * w1.w;
            }
        }
        #pragma unroll
        for (int e = 0; e < 8; ++e) {
            float v = acc[e];
            #pragma unroll
            for (int off = 32; off > 0; off >>= 1) v += __shfl_xor(v, off, 64);
            acc[e] = v + bg[e];
        }
        if (lane == 0) {
            float mx = acc[0];
            #pragma unroll
            for (int e = 1; e < 8; ++e) mx = fmaxf(mx, acc[e]);
            float p[8], s = 0.f;
            #pragma unroll
            for (int e = 0; e < 8; ++e) { p[e] = expf(acc[e] - mx); s += p[e]; }
            const float inv = 1.f / s;
            #pragma unroll
            for (int e = 0; e < 8; ++e) p[e] *= inv;

            int i0 = 0; float g0 = p[0];
            #pragma unroll
            for (int e = 1; e < 8; ++e) if (p[e] > g0) { g0 = p[e]; i0 = e; }
            int i1 = -1; float g1 = -1.f;
            #pragma unroll
            for (int e = 0; e < 8; ++e) if (e != i0 && p[e] > g1) { g1 = p[e]; i1 = e; }

            rec_idx[t] = (u32)i0 | ((u32)i1 << 4);
            rec_g[t] = make_float2(g0, g1);
        }
    } else if (bid < 4352) {
        // ------- pack W1: [E][768][3072] -> 256-row tiles, KC2=24 -------
        const int id = bid - 2048;               // e*288 + rt*12 + kc64
        const int e = id / 288, rem = id - e * 288;
        const int rt = rem / 12, kc = rem - rt * 12;
        pack_w_body(W1, w1g, rt, kc, e, D_DIM, F_DIM, 24, 256, 12);
    } else {
        // ------- pack W2: [E][3072][768] -> 256-row tiles, KC2=96 -------
        const int id = bid - 4352;               // e*288 + rt*48 + kc64
        const int e = id / 288, rem = id - e * 288;
        const int rt = rem / 48, kc = rem - rt * 48;
        pack_w_body(W2, w2g, rt, kc, e, F_DIM, D_DIM, 96, 256, 3);
    }
}

// ---------------------------------------------------------------------------
// Scatter: thread per token, wave-ballot aggregation -> <=8 atomics/wave.
// ---------------------------------------------------------------------------
__global__ __launch_bounds__(256) void moe_scatter(
    const u32* __restrict__ rec_idx, const float2* __restrict__ rec_g,
    int* __restrict__ counts, int* __restrict__ tokbuf,
    float* __restrict__ gatebuf)
{
    const int t = blockIdx.x * 256 + threadIdx.x;
    const int lane = threadIdx.x & 63;
    const u32 pk = rec_idx[t];
    const int i0 = pk & 15, i1 = (pk >> 4) & 15;
    const float2 g = rec_g[t];
    const u64 lmask = ((u64)1 << lane) - 1;

    #pragma unroll
    for (int e = 0; e < 8; ++e) {
        const u64 m0 = __ballot(i0 == e);
        const u64 m1 = __ballot(i1 == e);
        const int c0 = __popcll(m0);
        const int total = c0 + __popcll(m1);
        if (total > 0) {
            int base = 0;
            if (lane == 0) base = atomicAdd(&counts[e], total);
            base = __shfl(base, 0, 64);
            if (i0 == e) {
                const int p = base + __popcll(m0 & lmask);
                tokbuf[(size_t)e * CAP + p] = 2 * t;
                gatebuf[(size_t)e * CAP + p] = g.x;
            }
            if (i1 == e) {
                const int p = base + c0 + __popcll(m1 & lmask);
                tokbuf[(size_t)e * CAP + p] = 2 * t + 1;
                gatebuf[(size_t)e * CAP + p] = g.y;
            }
        }
    }
}

// tile table: for each expert, one tile per 128 entries
__global__ void scan_kernel(const int* __restrict__ counts,
                            int* __restrict__ te, int* __restrict__ tb,
                            int* __restrict__ ntile) {
    if (threadIdx.x == 0) {
        int nt = 0;
        for (int e = 0; e < E_EXP; ++e)
            for (int k = 0; k * 128 < counts[e]; ++k) {
                te[nt] = e; tb[nt] = k * 128; ++nt;
            }
        *ntile = nt;
    }
}

// ---------------------------------------------------------------------------
// pack_x: gather token rows -> swizzled bf16 [128][32]-chunk tiles.
// grid (NT_MAX, 12): block handles 64 d-cols = chunks kc*2, kc*2+1.
// ---------------------------------------------------------------------------
__global__ __launch_bounds__(256) void pack_x(
    const float* __restrict__ x, const int* __restrict__ counts,
    const int* __restrict__ te, const int* __restrict__ tb,
    const int* __restrict__ ntile, const int* __restrict__ tokbuf,
    u16* __restrict__ xg)
{
    const int bx = blockIdx.x, kc = blockIdx.y;
    if (bx >= *ntile) return;
    const int e = te[bx], base = tb[bx], cnt = counts[e];
    const int tid = threadIdx.x;
    const int r = tid >> 1, hf = tid & 1;
    int ent = base + r; if (ent >= cnt) ent = cnt - 1;
    const int tok = tokbuf[(size_t)e * CAP + ent] >> 1;
    const float* xr = x + (size_t)tok * D_DIM + kc * 64 + hf * 32;
    u16* xt = xg + ((size_t)bx * 24 + kc * 2 + hf) * 4096;
    #pragma unroll
    for (int j = 0; j < 4; ++j) {
        float4 a = *(const float4*)(xr + j * 8);
        float4 b = *(const float4*)(xr + j * 8 + 4);
        union { s8v v; u16 u[8]; } o;
        o.u[0] = f2bf(a.x); o.u[1] = f2bf(a.y); o.u[2] = f2bf(a.z); o.u[3] = f2bf(a.w);
        o.u[4] = f2bf(b.x); o.u[5] = f2bf(b.y); o.u[6] = f2bf(b.z); o.u[7] = f2bf(b.w);
        *(s8v*)&xt[(size_t)r * 32 + ((j ^ ((r >> 1) & 3)) * 8)] = o.v;
    }
}

// ---------------------------------------------------------------------------
// Shared GEMM step: 256(m)x128(n) block, 4 waves of 128x64, BK=32.
// Triple-buffered counted-vmcnt pipeline, ONE barrier per step (R6-verified):
//   vmcnt(6) [buf S complete] -> barrier -> stage(S+2) -> ds_read 12 frags ->
//   32 MFMA (compiler interleaves with counted lgkmcnt).
// Tail stages clamp to the last K-step (uniform ledger, in-bounds).
// LDS: 3 x (16KB A + 8KB B) = 72KB -> 2 blocks/CU.
// ---------------------------------------------------------------------------
#define G_STAGE(S, SBUF) do {                                                 \
    const int S__ = (S) < NS_ ? (S) : NS_ - 1;                                \
    const u16* An_ = Ab + (size_t)S__ * 8192 + w * 2048 + lane * 8;           \
    const u16* Bn_ = Bb + (size_t)S__ * 4096 + w * 1024 + lane * 8;           \
    u16* Ad_ = &Als[SBUF][w * 2048];                                          \
    u16* Bd_ = &Bls[SBUF][w * 1024];                                          \
    gld_lds16(An_,        Ad_);                                               \
    gld_lds16(An_ +  512, Ad_ +  512);                                        \
    gld_lds16(An_ + 1024, Ad_ + 1024);                                        \
    gld_lds16(An_ + 1536, Ad_ + 1536);                                        \
    gld_lds16(Bn_,        Bd_);                                               \
    gld_lds16(Bn_ +  512, Bd_ +  512);                                        \
} while (0)

#define G_STEP(S, BUF, B2) do {                                               \
    wait_vmcnt<6>();                                                          \
    bar_fenced();                                                             \
    G_STAGE((S) + 2, B2);                                                     \
    s8v af[8], bf[4];                                                         \
    _Pragma("unroll")                                                         \
    for (int mi = 0; mi < 8; ++mi)                                            \
        af[mi] = *(const s8v*)&Als[BUF][(wm*128 + mi*16 + ln)*32 + colU];     \
    _Pragma("unroll")                                                         \
    for (int ni = 0; ni < 4; ++ni)                                            \
        bf[ni] = *(const s8v*)&Bls[BUF][(wn*64 + ni*16 + ln)*32 + colU];      \
    __builtin_amdgcn_s_setprio(1);                                            \
    _Pragma("unroll")                                                         \
    for (int mi = 0; mi < 8; ++mi)                                            \
        _Pragma("unroll")                                                     \
        for (int ni = 0; ni < 4; ++ni)                                        \
            acc[mi][ni] = __builtin_amdgcn_mfma_f32_16x16x32_bf16(            \
                af[mi], bf[ni], acc[mi][ni], 0, 0, 0);                        \
    __builtin_amdgcn_s_setprio(0);                                            \
} while (0)

// ---------------------------------------------------------------------------
// Stage 1: per (entry-tile, f-tile256): C[m=f 256][n=entry 128], K=768.
// 24 steps.  XCD-chunked 1D grid: 1632 = 8 XCDs x (17 bx x 12 by).
// bid&7 = XCD -> each XCD owns a contiguous 17-tile bx chunk (~1 expert's
// A panels + 17 B tiles stay in that XCD's L2).
// Epilogue: bias + fast-erf GELU -> bf16 hg in s2-B 32-col layout.
// ---------------------------------------------------------------------------
__global__ __launch_bounds__(256, 2) void s1_gemm(
    const u16* __restrict__ xg, const u16* __restrict__ w1g,
    const float* __restrict__ b1, const int* __restrict__ te,
    const int* __restrict__ ntile, u16* __restrict__ hg)
{
    __shared__ __align__(16) u16 Als[3][8192];   // 256 rows x 32 per buf
    __shared__ __align__(16) u16 Bls[3][4096];   // 128 rows x 32 per buf
    const int bid = blockIdx.x;          // [0,1632)
    const int xcd = bid & 7;
    const int i   = bid >> 3;            // [0,204) = 17*12
    const int bx  = xcd * 17 + i / 12;   // entry tile
    const int by  = i % 12;              // 256-f tile
    if (bx >= *ntile) return;
    const int e = te[bx];
    const int NS_ = 24;

    const int tid  = threadIdx.x;
    const int w    = tid >> 6;
    const int lane = tid & 63;
    const int wm   = w & 1, wn = w >> 1;
    const int q    = lane >> 4, ln = lane & 15;
    const int colU = (q ^ ((ln >> 1) & 3)) * 8;

    const u16* Ab = w1g + (size_t)(e * 12 + by) * 24 * 8192;
    const u16* Bb = xg  + (size_t)bx * 24 * 4096;

    f4v acc[8][4];
    #pragma unroll
    for (int mi = 0; mi < 8; ++mi)
        #pragma unroll
        for (int ni = 0; ni < 4; ++ni) acc[mi][ni] = (f4v){0.f,0.f,0.f,0.f};

    // prologue: 2 stages in flight
    G_STAGE(0, 0);
    G_STAGE(1, 1);

    #pragma unroll 1
    for (int k = 0; k < 24; k += 3) {
        G_STEP(k,     0, 2);
        G_STEP(k + 1, 1, 0);
        G_STEP(k + 2, 2, 1);
    }
    wait_vmcnt<0>();

    // epilogue: f_local = wm*128 + mi*16 + q*4 (+r), entry = wn*64 + ni*16 + ln
    const float* b1e = b1 + (size_t)e * F_DIM + by * 256;
    #pragma unroll
    for (int mi = 0; mi < 8; ++mi) {
        const int floc = wm * 128 + mi * 16 + q * 4;
        const int kc2  = by * 8 + (floc >> 5);       // 32-f chunk index
        const int cg   = (floc >> 3) & 3;            // col-group within chunk
        const float4 bv = *(const float4*)&b1e[floc];
        #pragma unroll
        for (int ni = 0; ni < 4; ++ni) {
            const int rr = wn * 64 + ni * 16 + ln;
            uint2 pk;
            pk.x = cvt_pk_bf16(gelu_fast(acc[mi][ni][0] + bv.x),
                               gelu_fast(acc[mi][ni][1] + bv.y));
            pk.y = cvt_pk_bf16(gelu_fast(acc[mi][ni][2] + bv.z),
                               gelu_fast(acc[mi][ni][3] + bv.w));
            *(uint2*)&hg[((size_t)bx * 96 + kc2) * 4096 +
                         (size_t)rr * 32 + ((cg ^ ((rr >> 1) & 3)) * 8) +
                         (q & 1) * 4] = pk;
        }
    }
}

// ---------------------------------------------------------------------------
// Stage 2: per (entry-tile, d-tile256): C[m=d 256][n=entry 128], K=3072.
// 96 steps.  XCD-chunked 1D grid: 408 = 8 x (17 bx x 3 by).
// Epilogue: y[tokslot][d] = gate * C  (bf16 stores, no atomics).
// ---------------------------------------------------------------------------
__global__ __launch_bounds__(256, 2) void s2_gemm(
    const u16* __restrict__ hg, const u16* __restrict__ w2g,
    const int* __restrict__ counts, const int* __restrict__ te,
    const int* __restrict__ tb, const int* __restrict__ ntile,
    const int* __restrict__ tokbuf, const float* __restrict__ gatebuf,
    u16* __restrict__ y)
{
    __shared__ __align__(16) u16 Als[3][8192];   // 256 rows x 32 per buf
    __shared__ __align__(16) u16 Bls[3][4096];   // 128 rows x 32 per buf
    __shared__ int   sts[128];
    __shared__ float sg[128];
    const int bid = blockIdx.x;          // [0,408)
    const int xcd = bid & 7;
    const int i   = bid >> 3;            // [0,51) = 17*3
    const int bx  = xcd * 17 + i / 3;    // entry tile
    const int by  = i % 3;               // 256-d tile
    if (bx >= *ntile) return;
    const int e = te[bx], base = tb[bx], cnt = counts[e];
    const int NS_ = 96;

    const int tid  = threadIdx.x;
    const int w    = tid >> 6;
    const int lane = tid & 63;
    const int wm   = w & 1, wn = w >> 1;
    const int q    = lane >> 4, ln = lane & 15;
    const int colU = (q ^ ((ln >> 1) & 3)) * 8;

    if (tid < 128) {
        const int ent = base + tid;
        const bool v = ent < cnt;
        sts[tid] = v ? tokbuf[(size_t)e * CAP + ent] : -1;
        sg[tid]  = v ? gatebuf[(size_t)e * CAP + ent] : 0.f;
    }
    // drain the prefetch loads so the vmcnt ledger below is exact
    asm volatile("s_waitcnt vmcnt(0) lgkmcnt(0)" ::: "memory");
    bar_fenced();

    const u16* Ab = w2g + (size_t)(e * 3 + by) * 96 * 8192;
    const u16* Bb = hg  + (size_t)bx * 96 * 4096;

    f4v acc[8][4];
    #pragma unroll
    for (int mi = 0; mi < 8; ++mi)
        #pragma unroll
        for (int ni = 0; ni < 4; ++ni) acc[mi][ni] = (f4v){0.f,0.f,0.f,0.f};

    G_STAGE(0, 0);
    G_STAGE(1, 1);

    #pragma unroll 1
    for (int k = 0; k < 96; k += 3) {
        G_STEP(k,     0, 2);
        G_STEP(k + 1, 1, 0);
        G_STEP(k + 2, 2, 1);
    }
    wait_vmcnt<0>();

    // epilogue: d = by*256 + wm*128 + mi*16 + q*4, entry = wn*64 + ni*16 + ln
    #pragma unroll
    for (int ni = 0; ni < 4; ++ni) {
        const int rr = wn * 64 + ni * 16 + ln;
        const int ts = sts[rr];
        if (ts >= 0) {
            const float g = sg[rr];
            u16* yr = y + (size_t)ts * D_DIM + by * 256 + wm * 128 + q * 4;
            #pragma unroll
            for (int mi = 0; mi < 8; ++mi) {
                uint2 pk;
                pk.x = cvt_pk_bf16(g * acc[mi][ni][0], g * acc[mi][ni][1]);
                pk.y = cvt_pk_bf16(g * acc[mi][ni][2], g * acc[mi][ni][3]);
                *(uint2*)&yr[mi * 16] = pk;
            }
        }
    }
}

// out = g0*b2[i0] + g1*b2[i1] + y[2t] + y[2t+1]
__global__ __launch_bounds__(256) void combine_kernel(
    const u16* __restrict__ y, const u32* __restrict__ rec_idx,
    const float2* __restrict__ rec_g, const float* __restrict__ b2,
    float* __restrict__ out)
{
    const int gid = blockIdx.x * 256 + threadIdx.x;
    const int t = gid / 192;
    const int c = (gid - t * 192) * 4;
    const u32 pk = rec_idx[t];
    const int i0 = pk & 15, i1 = (pk >> 4) & 15;
    const float2 g = rec_g[t];
    union { uint2 p; u16 u[4]; } a, b;
    a.p = *(const uint2*)&y[(size_t)(2 * t) * D_DIM + c];
    b.p = *(const uint2*)&y[(size_t)(2 * t + 1) * D_DIM + c];
    const float4 ba = *(const float4*)&b2[(size_t)i0 * D_DIM + c];
    const float4 bb = *(const float4*)&b2[(size_t)i1 * D_DIM + c];
    float4 o;
    o.x = g.x * ba.x + g.y * bb.x + bf2f(a.u[0]) + bf2f(b.u[0]);
    o.y = g.x * ba.y + g.y * bb.y + bf2f(a.u[1]) + bf2f(b.u[1]);
    o.z = g.x * ba.z + g.y * bb.z + bf2f(a.u[2]) + bf2f(b.u[2]);
    o.w = g.x * ba.w + g.y * bb.w + bf2f(a.u[3]) + bf2f(b.u[3]);
    *(float4*)&out[(size_t)t * D_DIM + c] = o;
}

// ---------------------------------------------------------------------------
extern "C" void kernel_launch(void* const* d_in, const int* in_sizes, int n_in,
                              void* d_out, int out_size, void* d_ws, size_t ws_size,
                              hipStream_t stream) {
    const float* x  = (const float*)d_in[0];
    const float* Wg = (const float*)d_in[1];
    const float* bg = (const float*)d_in[2];
    const float* W1 = (const float*)d_in[3];
    const float* b1 = (const float*)d_in[4];
    const float* W2 = (const float*)d_in[5];
    const float* b2 = (const float*)d_in[6];
    float* out = (float*)d_out;

    // ws layout (~235 MB)
    char* ws = (char*)d_ws;
    size_t off = 0;
    u16* xg  = (u16*)(ws + off); off += (size_t)NT_MAX * 24 * 4096 * sizeof(u16);
    u16* w1g = (u16*)(ws + off); off += (size_t)E_EXP * F_DIM * D_DIM * sizeof(u16);
    u16* w2g = (u16*)(ws + off); off += (size_t)E_EXP * D_DIM * F_DIM * sizeof(u16);
    u16* hg  = (u16*)(ws + off); off += (size_t)NT_MAX * 96 * 4096 * sizeof(u16);
    u16* y   = (u16*)(ws + off); off += (size_t)2 * N_TOK * D_DIM * sizeof(u16);
    int* tokbuf = (int*)(ws + off);      off += (size_t)E_EXP * CAP * sizeof(int);
    float* gatebuf = (float*)(ws + off); off += (size_t)E_EXP * CAP * sizeof(float);
    u32* rec_idx = (u32*)(ws + off);     off += (size_t)N_TOK * sizeof(u32);
    float2* rec_g = (float2*)(ws + off); off += (size_t)N_TOK * sizeof(float2);
    int* counts = (int*)(ws + off);      off += 64;
    int* te     = (int*)(ws + off);      off += NT_MAX * sizeof(int);
    int* tb     = (int*)(ws + off);      off += NT_MAX * sizeof(int);
    int* ntile  = (int*)(ws + off);      off += 64;

    prep_kernel<<<6656, 256, 0, stream>>>(x, Wg, bg, W1, W2, rec_idx, rec_g,
                                          w1g, w2g, counts);
    moe_scatter<<<N_TOK / 256, 256, 0, stream>>>(rec_idx, rec_g, counts, tokbuf, gatebuf);
    scan_kernel<<<1, 64, 0, stream>>>(counts, te, tb, ntile);
    pack_x<<<dim3(NT_MAX, 12), 256, 0, stream>>>(x, counts, te, tb, ntile, tokbuf, xg);

    s1_gemm<<<NT_MAX * 12, 256, 0, stream>>>(xg, w1g, b1, te, ntile, hg);
    s2_gemm<<<NT_MAX * 3, 256, 0, stream>>>(hg, w2g, counts, te, tb, ntile,
                                            tokbuf, gatebuf, y);
    combine_kernel<<<(N_TOK * 192) / 256, 256, 0, stream>>>(y, rec_idx, rec_g, b2, out);
}